// Round 9
// baseline (522.510 us; speedup 1.0000x reference)
//
#include <hip/hip_runtime.h>
#include <stdint.h>

#define BATCH 4096
#define NEXP 64

typedef __bf16 bf16x8 __attribute__((ext_vector_type(8)));
typedef float f32x4 __attribute__((ext_vector_type(4)));
typedef float f32x8 __attribute__((ext_vector_type(8)));
typedef unsigned int u32x4 __attribute__((ext_vector_type(4)));
typedef unsigned short u16x4 __attribute__((ext_vector_type(4)));
typedef unsigned short u16x8 __attribute__((ext_vector_type(8)));

__device__ __forceinline__ unsigned short f2bf(float f) {
  unsigned u = __builtin_bit_cast(unsigned, f);
  u += 0x7fffu + ((u >> 16) & 1u);
  return (unsigned short)(u >> 16);
}

// async global->LDS, 16B per lane (MNet GEMM only).
__device__ __forceinline__ void async_copy16(const void* g, void* l) {
  __builtin_amdgcn_global_load_lds(
      (const __attribute__((address_space(1))) void*)(uintptr_t)g,
      (__attribute__((address_space(3))) void*)(uintptr_t)l, 16, 0, 0);
}

enum { AM_PLAIN = 0, AM_BN = 1 };

// ---------------------------------------------------------------------------
// MNet GEMM (unchanged).
// ---------------------------------------------------------------------------
template <int BM_, int BN_, int WR, int WC, int AMODE>
__global__ __launch_bounds__(256, 4) void gemm_k(
    const float* __restrict__ Af32, const float* __restrict__ scv,
    const float* __restrict__ shv, const float* __restrict__ alphaPtr,
    const unsigned short* __restrict__ PB, int K, int nsubsTot,
    float* __restrict__ Cp, const float* __restrict__ biasv, int N,
    int ktilesTot) {
  constexpr int MS = BM_ / 16;
  constexpr int NS = BN_ / 16;
  constexpr int WTM = BM_ / WR, WTN = BN_ / WC;
  constexpr int TM = WTM / 16, TN = WTN / 16;
  constexpr int PCH = MS / 2;

  __shared__ __align__(16) unsigned short As[2 * MS * 512];
  __shared__ __align__(16) unsigned short Bs[2 * NS * 512];

  const int tid = threadIdx.x;
  const int lane = tid & 63;
  const int wid = tid >> 6;
  const int wrow = wid / WC, wcol = wid % WC;

  const int m0 = blockIdx.x * BM_;
  const int ntile = blockIdx.y;
  const int n0 = ntile * BN_;

  float alpha = 0.f;
  if constexpr (AMODE == AM_BN) alpha = alphaPtr[0];

  f32x4 acc[TM][TN] = {};

  for (int kt = 0; kt < ktilesTot; ++kt) {
    const int k0 = kt * 64;

    for (int f = wid; f < 2 * NS; f += 4) {
      const int fkt = f / NS, fns = f % NS;
      const long fragIdx = (long)(k0 / 32 + fkt) * nsubsTot + (ntile * NS + fns);
      async_copy16(PB + fragIdx * 512 + lane * 8, &Bs[f * 512 + lane * 8]);
    }

#pragma unroll
    for (int p = 0; p < PCH; ++p) {
      const int id = p * 256 + tid;
      const int fA = id >> 6;
      const int q = id & 63;
      const int ksh = fA / MS, msub = fA % MS;
      const int kq = q >> 4, mrow = q & 15;
      const int m = msub * 16 + mrow;
      const int kg = k0 + ksh * 32 + kq * 8;
      const long mg = m0 + m;
      f32x8 vf;
      if constexpr (AMODE == AM_PLAIN) {
        const f32x4* src = (const f32x4*)(Af32 + mg * K + kg);
        f32x4 a0 = src[0], a1 = src[1];
#pragma unroll
        for (int j = 0; j < 4; ++j) { vf[j] = a0[j]; vf[4 + j] = a1[j]; }
      } else {
        const f32x4* src = (const f32x4*)(Af32 + mg * K + kg);
        f32x4 a0 = src[0], a1 = src[1];
        f32x4 s0 = *(const f32x4*)(scv + kg), s1 = *(const f32x4*)(scv + kg + 4);
        f32x4 h0 = *(const f32x4*)(shv + kg), h1 = *(const f32x4*)(shv + kg + 4);
#pragma unroll
        for (int j = 0; j < 4; ++j) {
          float v = fmaf(a0[j], s0[j], h0[j]);
          vf[j] = v >= 0.f ? v : alpha * v;
          float v2 = fmaf(a1[j], s1[j], h1[j]);
          vf[4 + j] = v2 >= 0.f ? v2 : alpha * v2;
        }
      }
      bf16x8 ob = __builtin_convertvector(vf, bf16x8);
      *(u16x8*)&As[id * 8] = __builtin_bit_cast(u16x8, ob);
    }
    __syncthreads();

#pragma unroll
    for (int ks = 0; ks < 2; ++ks) {
      bf16x8 af[TM], bfr[TN];
#pragma unroll
      for (int i = 0; i < TM; ++i) {
        const int msub = wrow * TM + i;
        af[i] = __builtin_bit_cast(
            bf16x8, *(const u32x4*)&As[(ks * MS + msub) * 512 + lane * 8]);
      }
#pragma unroll
      for (int j = 0; j < TN; ++j) {
        const int nsub = wcol * TN + j;
        bfr[j] = __builtin_bit_cast(
            bf16x8, *(const u32x4*)&Bs[(ks * NS + nsub) * 512 + lane * 8]);
      }
#pragma unroll
      for (int i = 0; i < TM; ++i)
#pragma unroll
        for (int j = 0; j < TN; ++j)
          acc[i][j] = __builtin_amdgcn_mfma_f32_16x16x32_bf16(af[i], bfr[j],
                                                              acc[i][j], 0, 0, 0);
    }
    __syncthreads();
  }

  const int q = lane >> 4, nn = lane & 15;
#pragma unroll
  for (int i = 0; i < TM; ++i) {
    const int rowb = m0 + wrow * WTM + i * 16 + q * 4;
#pragma unroll
    for (int j = 0; j < TN; ++j) {
      const int col = n0 + wcol * WTN + j * 16 + nn;
      const float bv = biasv ? biasv[col] : 0.f;
#pragma unroll
      for (int r = 0; r < 4; ++r)
        Cp[(long)(rowb + r) * N + col] = acc[i][j][r] + bv;
    }
  }
}

// ---------------------------------------------------------------------------
// Expert GEMM (round-9): K split into KHALVES per-dispatch slices so the
// resident A tile is KT2=KT2F/KHALVES subtiles -> areg = 4*KT2*4 VGPRs
// (64 for KT2=4). Round-8 evidence: VGPR_Count=124 < 128 needed => compiler
// rematerialized A loads every kt (the ~75% stall). Now A is truly resident;
// ring-4 B prefetch covers the only global loads in the loop.
// Partial p = khalf*S + slice; bias folded in khalf 0 only (fp32-exact).
// ---------------------------------------------------------------------------
template <int BN_, int KE_, int EPB, int NTILE, int KHALVES>
__global__ __launch_bounds__(256, 2) void egemm_k(
    const unsigned short* __restrict__ zpk, const float* __restrict__ wnT,
    const float* __restrict__ bias, const unsigned short* __restrict__ PB,
    float* __restrict__ Cbase, long partStride, int N, int nsubsTot) {
  constexpr int KT2F = KE_ / 32;           // K-subtiles per expert (full)
  constexpr int KT2 = KT2F / KHALVES;      // per dispatch-slice
  constexpr int LK = (KT2 == 8) ? 3 : (KT2 == 4) ? 2 : 1;
  constexpr int NS = BN_ / 16;
  constexpr int TN = NS / 4;
  constexpr int TM = 4;
  constexpr int S = NEXP / EPB;
  constexpr int NC = NTILE * S * KHALVES;  // combos (low grid bits -> XCD)
  constexpr int T = EPB * KT2;
  constexpr int U = ((KT2 & 3) == 0) ? 1 : (4 / KT2);  // slot compile-time

  const int tid = threadIdx.x, lane = tid & 63, wid = tid >> 6;
  const int bx = blockIdx.x;
  const int combo = bx % NC;
  const int mb = bx / NC;
  const int ntile = combo % NTILE;
  const int rest = combo / NTILE;
  const int slice = rest % S;
  const int khalf = rest / S;
  const int e0 = slice * EPB;
  const int n0 = ntile * BN_;
  float* __restrict__ Cp = Cbase + (long)(khalf * S + slice) * partStride;
  const int nn = lane & 15, q = lane >> 4;
  const bool addBias = (KHALVES == 1) || (khalf == 0);

  // Resident A fragments for this k-half (expert-invariant). 4*KT2 u32x4.
  const unsigned short* zb =
      zpk + (long)mb * (KT2F * 4 * 512) + (long)khalf * (KT2 * 4 * 512);
  u32x4 areg[TM][KT2];
#pragma unroll
  for (int i = 0; i < TM; ++i)
#pragma unroll
    for (int kt = 0; kt < KT2; ++kt)
      areg[i][kt] = *(const u32x4*)(zb + (kt * 4 + i) * 512 + lane * 8);

  const long kstr = (long)nsubsTot * 512;
  const unsigned short* Bq = PB + ((long)e0 * KT2F + khalf * KT2) * kstr +
                             ((long)ntile * NS + wid * TN) * 512 + lane * 8;
  auto baddr = [&](int u) {
    const int ei = u >> LK, kt = u & (KT2 - 1);
    return Bq + ((long)ei * KT2F + kt) * kstr;
  };

  u32x4 ring[4][TN];
#pragma unroll
  for (int t = 0; t < 4; ++t) {
    const unsigned short* a = baddr(t < T ? t : T - 1);
#pragma unroll
    for (int j = 0; j < TN; ++j) ring[t][j] = *(const u32x4*)(a + j * 512);
  }

  f32x4 mainAcc[TM][TN] = {};

  for (int eb = 0; eb < EPB; eb += U) {
#pragma unroll
    for (int uu = 0; uu < U; ++uu) {
      const int ei = eb + uu;
      const int e = e0 + ei;
      f32x4 tmp[TM][TN];
#pragma unroll
      for (int j = 0; j < TN; ++j) {
        const float bv =
            addBias ? bias[(long)e * N + n0 + wid * (TN * 16) + j * 16 + nn]
                    : 0.f;
        f32x4 t4 = {bv, bv, bv, bv};
#pragma unroll
        for (int i = 0; i < TM; ++i) tmp[i][j] = t4;
      }
#pragma unroll
      for (int kt = 0; kt < KT2; ++kt) {
        const int slot = (uu * KT2 + kt) & 3;  // compile-time (eb*KT2 % 4 == 0)
#pragma unroll
        for (int i = 0; i < TM; ++i) {
          bf16x8 af = __builtin_bit_cast(bf16x8, areg[i][kt]);
#pragma unroll
          for (int j = 0; j < TN; ++j)
            tmp[i][j] = __builtin_amdgcn_mfma_f32_16x16x32_bf16(
                af, __builtin_bit_cast(bf16x8, ring[slot][j]), tmp[i][j], 0, 0,
                0);
        }
        {
          const int u = ei * KT2 + kt;
          const int un = (u + 4 < T) ? (u + 4) : (T - 1);
          const unsigned short* a = baddr(un);
#pragma unroll
          for (int j = 0; j < TN; ++j)
            ring[slot][j] = *(const u32x4*)(a + j * 512);
        }
      }
#pragma unroll
      for (int i = 0; i < TM; ++i) {
        const int rowb = mb * 64 + i * 16 + q * 4;
        f32x4 wn4 = *(const f32x4*)(wnT + (long)e * BATCH + rowb);
#pragma unroll
        for (int j = 0; j < TN; ++j) mainAcc[i][j] += wn4 * tmp[i][j];
      }
    }
  }

#pragma unroll
  for (int i = 0; i < TM; ++i) {
    const int rowb = mb * 64 + i * 16 + q * 4;
#pragma unroll
    for (int j = 0; j < TN; ++j) {
      const int col = n0 + wid * (TN * 16) + j * 16 + nn;
#pragma unroll
      for (int r = 0; r < 4; ++r)
        Cp[(long)(rowb + r) * N + col] = mainAcc[i][j][r];
    }
  }
}

// ---------------------------------------------------------------------------
// Fused hbuild+stats, COALESCED (C=256): thread tid -> fixed columns
// c0=(tid&63)*4, row group tid>>6; block bx covers rows [bx*8, bx*8+8).
// Sums nparts partials -> H in place; atomically adds col sums to S1/S2.
// ---------------------------------------------------------------------------
__global__ void hstats_k(float* __restrict__ P, long partStride, int nparts,
                         float* __restrict__ S1, float* __restrict__ S2) {
  const int c0 = (threadIdx.x & 63) * 4;
  const int rg = threadIdx.x >> 6;
  const int rb = blockIdx.x * 8;
  f32x4 s = {0.f, 0.f, 0.f, 0.f}, s2 = {0.f, 0.f, 0.f, 0.f};
#pragma unroll
  for (int it = 0; it < 2; ++it) {
    const long r = rb + it * 4 + rg;
    f32x4 x = *(const f32x4*)(P + r * 256 + c0);
    for (int p = 1; p < nparts; ++p)
      x += *(const f32x4*)(P + p * partStride + r * 256 + c0);
    *(f32x4*)(P + r * 256 + c0) = x;
    s += x;
    s2 += x * x;
  }
  __shared__ f32x4 sb[256], qb[256];
  sb[threadIdx.x] = s;
  qb[threadIdx.x] = s2;
  __syncthreads();
  if (threadIdx.x < 64) {
    f32x4 ts = sb[threadIdx.x] + sb[64 + threadIdx.x] + sb[128 + threadIdx.x] +
               sb[192 + threadIdx.x];
    f32x4 tq = qb[threadIdx.x] + qb[64 + threadIdx.x] + qb[128 + threadIdx.x] +
               qb[192 + threadIdx.x];
    const int c = threadIdx.x * 4;
#pragma unroll
    for (int j = 0; j < 4; ++j) {
      atomicAdd(&S1[c + j], ts[j]);
      atomicAdd(&S2[c + j], tq[j]);
    }
  }
}

// BN stats (MNet path, unchanged).
__global__ void stats_k(const float* __restrict__ H, int C,
                        const float* __restrict__ g, const float* __restrict__ b,
                        float* __restrict__ scv, float* __restrict__ shv) {
  const int c0 = blockIdx.x * 4;
  f32x4 s = {0.f, 0.f, 0.f, 0.f}, s2 = {0.f, 0.f, 0.f, 0.f};
  for (int r = threadIdx.x; r < BATCH; r += 256) {
    f32x4 x = *(const f32x4*)(H + (long)r * C + c0);
    s += x;
    s2 += x * x;
  }
  __shared__ f32x4 sb[256], qb[256];
  sb[threadIdx.x] = s;
  qb[threadIdx.x] = s2;
  __syncthreads();
  for (int st = 128; st > 0; st >>= 1) {
    if (threadIdx.x < st) {
      sb[threadIdx.x] += sb[threadIdx.x + st];
      qb[threadIdx.x] += qb[threadIdx.x + st];
    }
    __syncthreads();
  }
  if (threadIdx.x < 4) {
    const int c = c0 + threadIdx.x;
    float mu = sb[0][threadIdx.x] * (1.f / BATCH);
    float var = qb[0][threadIdx.x] * (1.f / BATCH) - mu * mu;
    float isig = 1.f / sqrtf(var + 1e-5f);
    float sc_ = g[c] * isig;
    scv[c] = sc_;
    shv[c] = b[c] - mu * sc_;
  }
}

// zpk = packed-A-fragment bf16 of prelu(bn(H)); BN inline from S1/S2.
__global__ void zbuild_pk(const float* __restrict__ H,
                          const float* __restrict__ S1,
                          const float* __restrict__ S2,
                          const float* __restrict__ g,
                          const float* __restrict__ b,
                          const float* __restrict__ alphaPtr,
                          unsigned short* __restrict__ zpk) {
  const int c = blockIdx.x * 256 + threadIdx.x;  // 131072 total
  const float alpha = alphaPtr[0];
  const int mb = c >> 11, r = c & 2047;
  const int kt = r >> 8, q2 = r & 255;
  const int msub = q2 >> 6, ln = q2 & 63;
  const int row = mb * 64 + msub * 16 + (ln & 15);
  const int col = kt * 32 + (ln >> 4) * 8;
  const float* src = H + (long)row * 256 + col;
  u16x8 o;
#pragma unroll
  for (int h = 0; h < 2; ++h) {
    f32x4 a = *(const f32x4*)(src + h * 4);
    f32x4 s1 = *(const f32x4*)(S1 + col + h * 4);
    f32x4 s2 = *(const f32x4*)(S2 + col + h * 4);
    f32x4 gv = *(const f32x4*)(g + col + h * 4);
    f32x4 bv = *(const f32x4*)(b + col + h * 4);
#pragma unroll
    for (int j = 0; j < 4; ++j) {
      float mu = s1[j] * (1.f / BATCH);
      float var = s2[j] * (1.f / BATCH) - mu * mu;
      float sc_ = gv[j] / sqrtf(var + 1e-5f);
      float sh_ = bv[j] - mu * sc_;
      float v = fmaf(a[j], sc_, sh_);
      v = v >= 0.f ? v : alpha * v;
      o[h * 4 + j] = f2bf(v);
    }
  }
  *(u16x8*)(zpk + (long)c * 8) = o;
}

// w = prelu(bn(H3)) fp32, + global sum
__global__ void wbuild_k(const float* __restrict__ G, const float* __restrict__ scv,
                         const float* __restrict__ shv,
                         const float* __restrict__ alphaPtr,
                         float* __restrict__ w, float* __restrict__ wsum) {
  const int idx = blockIdx.x * 256 + threadIdx.x;  // 65536 threads
  const float alpha = alphaPtr[0];
  const int c0 = (idx * 4) & 63;
  f32x4 x = *(const f32x4*)(G + (long)idx * 4);
  f32x4 sv = *(const f32x4*)(scv + c0);
  f32x4 hv = *(const f32x4*)(shv + c0);
  f32x4 o;
  float part = 0.f;
#pragma unroll
  for (int j = 0; j < 4; ++j) {
    float v = fmaf(x[j], sv[j], hv[j]);
    v = v >= 0.f ? v : alpha * v;
    o[j] = v;
    part += v;
  }
  *(f32x4*)(w + (long)idx * 4) = o;
  __shared__ float sb[256];
  sb[threadIdx.x] = part;
  __syncthreads();
  for (int st = 128; st > 0; st >>= 1) {
    if (threadIdx.x < st) sb[threadIdx.x] += sb[threadIdx.x + st];
    __syncthreads();
  }
  if (threadIdx.x == 0) atomicAdd(wsum, sb[0]);
}

// Fused: wnT (blocks 0..1023) ; x0 -> packed bf16 (blocks 1024..1151).
__global__ void wnTcast_k(const float* __restrict__ w,
                          const float* __restrict__ wsum,
                          float* __restrict__ wnT, const float* __restrict__ x0,
                          unsigned short* __restrict__ x0pk) {
  const int bx = blockIdx.x;
  if (bx < 1024) {
    const int idx = bx * 256 + threadIdx.x;
    const int e = idx >> 12, b = idx & 4095;
    wnT[idx] = w[(long)b * NEXP + e] * (1.0f / wsum[0]);
  } else {
    const int c = (bx - 1024) * 256 + threadIdx.x;  // 32768
    const int mb = c >> 9, r = c & 511;
    const int kt = r >> 8, q2 = r & 255;
    const int msub = q2 >> 6, ln = q2 & 63;
    const int row = mb * 64 + msub * 16 + (ln & 15);
    const int col = kt * 32 + (ln >> 4) * 8;
    const float* src = x0 + (long)row * 64 + col;
    f32x4 a0 = *(const f32x4*)src, a1 = *(const f32x4*)(src + 4);
    u16x8 o;
#pragma unroll
    for (int j = 0; j < 4; ++j) {
      o[j] = f2bf(a0[j]);
      o[4 + j] = f2bf(a1[j]);
    }
    *(u16x8*)(x0pk + (long)c * 8) = o;
  }
}

// Fused prepack: all 7 weight tensors -> fragment-major bf16.
__global__ void prepackall_k(
    const float* __restrict__ w0, const float* __restrict__ w1,
    const float* __restrict__ w2, const float* __restrict__ w3,
    const float* __restrict__ w4, const float* __restrict__ w5,
    const float* __restrict__ w6, unsigned short* __restrict__ PB) {
  const int t = blockIdx.x * 256 + threadIdx.x;
  const float* W;
  int nsubs, shI;
  long loc;
  if (t < 4096) { W = w0; nsubs = 16; shI = 7; loc = t; }                 // mW1
  else if (t < 8192) { W = w1; nsubs = 8; shI = 8; loc = t - 4096; }      // mW2
  else if (t < 9216) { W = w2; nsubs = 4; shI = 7; loc = t - 8192; }      // mW3
  else if (t < 140288) { W = w3; nsubs = 16; shI = 6; loc = t - 9216; }   // enc0
  else if (t < 664576) { W = w4; nsubs = 16; shI = 8; loc = t - 140288; } // enc1
  else if (t < 1188864) { W = w5; nsubs = 16; shI = 8; loc = t - 664576; }// dec0
  else if (t < 1319936) { W = w6; nsubs = 4; shI = 8; loc = t - 1188864; }// dec1
  else return;
  const int lane = (int)(loc & 63);
  const long frag = loc >> 6;
  const int nsub = (int)(frag % nsubs);
  const long ktile = frag / nsubs;
  const int n = nsub * 16 + (lane & 15);
  const int k = (int)(ktile * 32 + (lane >> 4) * 8);
  const int e = k >> shI;
  const int i0 = k & ((1 << shI) - 1);
  const int O = nsubs * 16;
  const float* src = W + ((long)e * O + n) * (1 << shI) + i0;
  f32x4 a0 = *(const f32x4*)src, a1 = *(const f32x4*)(src + 4);
  u16x8 o;
#pragma unroll
  for (int j = 0; j < 4; ++j) {
    o[j] = f2bf(a0[j]);
    o[4 + j] = f2bf(a1[j]);
  }
  *(u16x8*)(PB + (long)t * 8) = o;
}

__global__ void reduceN_k(const float* __restrict__ P, long partStride, int nparts,
                          float* __restrict__ out, int total4) {
  const int idx = blockIdx.x * 256 + threadIdx.x;
  if (idx >= total4) return;
  f32x4 s = {0.f, 0.f, 0.f, 0.f};
  for (int p = 0; p < nparts; ++p)
    s += *(const f32x4*)(P + p * partStride + (long)idx * 4);
  *(f32x4*)(out + (long)idx * 4) = s;
}

// ---------------------------------------------------------------------------
extern "C" void kernel_launch(void* const* d_in, const int* in_sizes, int n_in,
                              void* d_out, int out_size, void* d_ws, size_t ws_size,
                              hipStream_t stream) {
  const float* m0 = (const float*)d_in[0];
  const float* x0 = (const float*)d_in[1];
  const float* mW1 = (const float*)d_in[2];
  const float* mb1 = (const float*)d_in[3];
  const float* mg1 = (const float*)d_in[4];
  const float* mbe1 = (const float*)d_in[5];
  const float* ma1 = (const float*)d_in[6];
  const float* mW2 = (const float*)d_in[7];
  const float* mb2 = (const float*)d_in[8];
  const float* mg2 = (const float*)d_in[9];
  const float* mbe2 = (const float*)d_in[10];
  const float* ma2 = (const float*)d_in[11];
  const float* mW3 = (const float*)d_in[12];
  const float* mb3 = (const float*)d_in[13];
  const float* mg3 = (const float*)d_in[14];
  const float* mbe3 = (const float*)d_in[15];
  const float* ma3 = (const float*)d_in[16];
  const float* Wenc0 = (const float*)d_in[17];
  const float* benc0 = (const float*)d_in[18];
  const float* Wenc1 = (const float*)d_in[19];
  const float* benc1 = (const float*)d_in[20];
  const float* Wdec0 = (const float*)d_in[21];
  const float* bdec0 = (const float*)d_in[22];
  const float* Wdec1 = (const float*)d_in[23];
  const float* bdec1 = (const float*)d_in[24];
  const float* bng = (const float*)d_in[25];
  const float* bnb = (const float*)d_in[26];
  const float* aexp = (const float*)d_in[27];

  // Partial count for N=256 layers: KHALVES(2) x slices(4) = 8 -> 32 MB.
  // Fall back to slices=2 (4 partials, 16 MB) if workspace is tight.
  const bool big = ws_size >= (size_t)62 * 1024 * 1024;
  const int NPARTS = big ? 8 : 4;

  char* base = (char*)d_ws;
  size_t off = 0;
  auto alloc = [&](size_t bytes) {
    void* p = base + off;
    off = (off + bytes + 255) & ~(size_t)255;
    return p;
  };
  unsigned short* PB = (unsigned short*)alloc(1319936L * 16);  // 20.2 MB
  const long CO_mW2 = 4096, CO_mW3 = 8192, CO_e0 = 9216, CO_e1 = 140288,
             CO_d0 = 664576, CO_d1 = 1188864;
  float* Pb = (float*)alloc((size_t)NPARTS * BATCH * 256 * 4);
  float* P0 = Pb;
  float* P1 = Pb + (long)BATCH * 256;
  unsigned short* zApk = (unsigned short*)alloc(BATCH * 256 * 2);
  unsigned short* zBpk = (unsigned short*)alloc(BATCH * 256 * 2);
  unsigned short* x0pk = (unsigned short*)alloc(BATCH * 64 * 2);
  float* wbuf = (float*)alloc(BATCH * 64 * 4);
  float* wnT = (float*)alloc((size_t)NEXP * BATCH * 4);
  float* scv = (float*)alloc(256 * 4);
  float* shv = (float*)alloc(256 * 4);
  float* zeroBuf = (float*)alloc(8192);
  float* wsum = zeroBuf;
  float* S1a = zeroBuf + 256, *S2a = zeroBuf + 512;
  float* S1b = zeroBuf + 768, *S2b = zeroBuf + 1024;
  float* S1c = zeroBuf + 1280, *S2c = zeroBuf + 1536;

  const dim3 blk(256);
  const long PS = BATCH * 256;

  hipMemsetAsync(zeroBuf, 0, 8192, stream);
  prepackall_k<<<5156, blk, 0, stream>>>(mW1, mW2, mW3, Wenc0, Wenc1, Wdec0,
                                         Wdec1, PB);

  // ---- MNet
  gemm_k<64, 128, 2, 2, AM_PLAIN><<<dim3(64, 2, 1), blk, 0, stream>>>(
      m0, nullptr, nullptr, nullptr, PB, 128, 16, P0, mb1, 256, 2);
  stats_k<<<64, blk, 0, stream>>>(P0, 256, mg1, mbe1, scv, shv);
  gemm_k<64, 128, 2, 2, AM_BN><<<dim3(64, 1, 1), blk, 0, stream>>>(
      P0, scv, shv, ma1, PB + CO_mW2 * 8, 256, 8, P1, mb2, 128, 4);
  stats_k<<<32, blk, 0, stream>>>(P1, 128, mg2, mbe2, scv, shv);
  gemm_k<64, 64, 2, 2, AM_BN><<<dim3(64, 1, 1), blk, 0, stream>>>(
      P1, scv, shv, ma2, PB + CO_mW3 * 8, 128, 4, P0, mb3, 64, 2);
  stats_k<<<16, blk, 0, stream>>>(P0, 64, mg3, mbe3, scv, shv);
  wbuild_k<<<256, blk, 0, stream>>>(P0, scv, shv, ma3, wbuf, wsum);
  wnTcast_k<<<1152, blk, 0, stream>>>(wbuf, wsum, wnT, x0, x0pk);

  if (big) {
    // enc0: KE=64 (KT2F=2), no k-split (areg already fits), 4 slices.
    egemm_k<128, 64, 16, 2, 1><<<dim3(512), blk, 0, stream>>>(
        x0pk, wnT, benc0, PB + CO_e0 * 8, Pb, PS, 256, 16);
    hstats_k<<<512, blk, 0, stream>>>(Pb, PS, 4, S1a, S2a);
    zbuild_pk<<<512, blk, 0, stream>>>(Pb, S1a, S2a, bng, bnb, aexp, zApk);

    // enc1: KE=256 -> KT2=4, 4 slices x 2 khalves = 8 partials, 1024 blocks.
    egemm_k<128, 256, 16, 2, 2><<<dim3(1024), blk, 0, stream>>>(
        zApk, wnT, benc1, PB + CO_e1 * 8, Pb, PS, 256, 16);
    hstats_k<<<512, blk, 0, stream>>>(Pb, PS, 8, S1b, S2b);
    zbuild_pk<<<512, blk, 0, stream>>>(Pb, S1b, S2b, bng, bnb, aexp, zBpk);

    // dec0
    egemm_k<128, 256, 16, 2, 2><<<dim3(1024), blk, 0, stream>>>(
        zBpk, wnT, bdec0, PB + CO_d0 * 8, Pb, PS, 256, 16);
    hstats_k<<<512, blk, 0, stream>>>(Pb, PS, 8, S1c, S2c);
    zbuild_pk<<<512, blk, 0, stream>>>(Pb, S1c, S2c, bng, bnb, aexp, zApk);

    // dec1: N=64, 8 slices x 2 khalves = 16 partials of [4096,64].
    egemm_k<64, 256, 8, 1, 2><<<dim3(1024), blk, 0, stream>>>(
        zApk, wnT, bdec1, PB + CO_d1 * 8, Pb, (long)BATCH * 64, 64, 4);
    reduceN_k<<<256, blk, 0, stream>>>(Pb, (long)BATCH * 64, 16,
                                       (float*)d_out, 65536);
  } else {
    // tight-ws fallback: 2 slices (EPB=32) -> 4 partials.
    egemm_k<128, 64, 32, 2, 1><<<dim3(256), blk, 0, stream>>>(
        x0pk, wnT, benc0, PB + CO_e0 * 8, Pb, PS, 256, 16);
    hstats_k<<<512, blk, 0, stream>>>(Pb, PS, 2, S1a, S2a);
    zbuild_pk<<<512, blk, 0, stream>>>(Pb, S1a, S2a, bng, bnb, aexp, zApk);

    egemm_k<128, 256, 32, 2, 2><<<dim3(512), blk, 0, stream>>>(
        zApk, wnT, benc1, PB + CO_e1 * 8, Pb, PS, 256, 16);
    hstats_k<<<512, blk, 0, stream>>>(Pb, PS, 4, S1b, S2b);
    zbuild_pk<<<512, blk, 0, stream>>>(Pb, S1b, S2b, bng, bnb, aexp, zBpk);

    egemm_k<128, 256, 32, 2, 2><<<dim3(512), blk, 0, stream>>>(
        zBpk, wnT, bdec0, PB + CO_d0 * 8, Pb, PS, 256, 16);
    hstats_k<<<512, blk, 0, stream>>>(Pb, PS, 4, S1c, S2c);
    zbuild_pk<<<512, blk, 0, stream>>>(Pb, S1c, S2c, bng, bnb, aexp, zApk);

    egemm_k<64, 256, 8, 1, 2><<<dim3(1024), blk, 0, stream>>>(
        zApk, wnT, bdec1, PB + CO_d1 * 8, Pb, (long)BATCH * 64, 64, 4);
    reduceN_k<<<256, blk, 0, stream>>>(Pb, (long)BATCH * 64, 16,
                                       (float*)d_out, 65536);
  }

  (void)in_sizes; (void)n_in; (void)out_size;
}

// Round 10
// 517.746 us; speedup vs baseline: 1.0092x; 1.0092x over previous
//
#include <hip/hip_runtime.h>
#include <stdint.h>

#define BATCH 4096
#define NEXP 64

typedef __bf16 bf16x8 __attribute__((ext_vector_type(8)));
typedef float f32x4 __attribute__((ext_vector_type(4)));
typedef float f32x8 __attribute__((ext_vector_type(8)));
typedef unsigned int u32x4 __attribute__((ext_vector_type(4)));
typedef unsigned short u16x4 __attribute__((ext_vector_type(4)));
typedef unsigned short u16x8 __attribute__((ext_vector_type(8)));

__device__ __forceinline__ unsigned short f2bf(float f) {
  unsigned u = __builtin_bit_cast(unsigned, f);
  u += 0x7fffu + ((u >> 16) & 1u);
  return (unsigned short)(u >> 16);
}

// async global->LDS, 16B per lane (MNet GEMM only).
__device__ __forceinline__ void async_copy16(const void* g, void* l) {
  __builtin_amdgcn_global_load_lds(
      (const __attribute__((address_space(1))) void*)(uintptr_t)g,
      (__attribute__((address_space(3))) void*)(uintptr_t)l, 16, 0, 0);
}

enum { AM_PLAIN = 0, AM_BN = 1 };

// ---------------------------------------------------------------------------
// MNet GEMM (unchanged).
// ---------------------------------------------------------------------------
template <int BM_, int BN_, int WR, int WC, int AMODE>
__global__ __launch_bounds__(256, 4) void gemm_k(
    const float* __restrict__ Af32, const float* __restrict__ scv,
    const float* __restrict__ shv, const float* __restrict__ alphaPtr,
    const unsigned short* __restrict__ PB, int K, int nsubsTot,
    float* __restrict__ Cp, const float* __restrict__ biasv, int N,
    int ktilesTot) {
  constexpr int MS = BM_ / 16;
  constexpr int NS = BN_ / 16;
  constexpr int WTM = BM_ / WR, WTN = BN_ / WC;
  constexpr int TM = WTM / 16, TN = WTN / 16;
  constexpr int PCH = MS / 2;

  __shared__ __align__(16) unsigned short As[2 * MS * 512];
  __shared__ __align__(16) unsigned short Bs[2 * NS * 512];

  const int tid = threadIdx.x;
  const int lane = tid & 63;
  const int wid = tid >> 6;
  const int wrow = wid / WC, wcol = wid % WC;

  const int m0 = blockIdx.x * BM_;
  const int ntile = blockIdx.y;
  const int n0 = ntile * BN_;

  float alpha = 0.f;
  if constexpr (AMODE == AM_BN) alpha = alphaPtr[0];

  f32x4 acc[TM][TN] = {};

  for (int kt = 0; kt < ktilesTot; ++kt) {
    const int k0 = kt * 64;

    for (int f = wid; f < 2 * NS; f += 4) {
      const int fkt = f / NS, fns = f % NS;
      const long fragIdx = (long)(k0 / 32 + fkt) * nsubsTot + (ntile * NS + fns);
      async_copy16(PB + fragIdx * 512 + lane * 8, &Bs[f * 512 + lane * 8]);
    }

#pragma unroll
    for (int p = 0; p < PCH; ++p) {
      const int id = p * 256 + tid;
      const int fA = id >> 6;
      const int q = id & 63;
      const int ksh = fA / MS, msub = fA % MS;
      const int kq = q >> 4, mrow = q & 15;
      const int m = msub * 16 + mrow;
      const int kg = k0 + ksh * 32 + kq * 8;
      const long mg = m0 + m;
      f32x8 vf;
      if constexpr (AMODE == AM_PLAIN) {
        const f32x4* src = (const f32x4*)(Af32 + mg * K + kg);
        f32x4 a0 = src[0], a1 = src[1];
#pragma unroll
        for (int j = 0; j < 4; ++j) { vf[j] = a0[j]; vf[4 + j] = a1[j]; }
      } else {
        const f32x4* src = (const f32x4*)(Af32 + mg * K + kg);
        f32x4 a0 = src[0], a1 = src[1];
        f32x4 s0 = *(const f32x4*)(scv + kg), s1 = *(const f32x4*)(scv + kg + 4);
        f32x4 h0 = *(const f32x4*)(shv + kg), h1 = *(const f32x4*)(shv + kg + 4);
#pragma unroll
        for (int j = 0; j < 4; ++j) {
          float v = fmaf(a0[j], s0[j], h0[j]);
          vf[j] = v >= 0.f ? v : alpha * v;
          float v2 = fmaf(a1[j], s1[j], h1[j]);
          vf[4 + j] = v2 >= 0.f ? v2 : alpha * v2;
        }
      }
      bf16x8 ob = __builtin_convertvector(vf, bf16x8);
      *(u16x8*)&As[id * 8] = __builtin_bit_cast(u16x8, ob);
    }
    __syncthreads();

#pragma unroll
    for (int ks = 0; ks < 2; ++ks) {
      bf16x8 af[TM], bfr[TN];
#pragma unroll
      for (int i = 0; i < TM; ++i) {
        const int msub = wrow * TM + i;
        af[i] = __builtin_bit_cast(
            bf16x8, *(const u32x4*)&As[(ks * MS + msub) * 512 + lane * 8]);
      }
#pragma unroll
      for (int j = 0; j < TN; ++j) {
        const int nsub = wcol * TN + j;
        bfr[j] = __builtin_bit_cast(
            bf16x8, *(const u32x4*)&Bs[(ks * NS + nsub) * 512 + lane * 8]);
      }
#pragma unroll
      for (int i = 0; i < TM; ++i)
#pragma unroll
        for (int j = 0; j < TN; ++j)
          acc[i][j] = __builtin_amdgcn_mfma_f32_16x16x32_bf16(af[i], bfr[j],
                                                              acc[i][j], 0, 0, 0);
    }
    __syncthreads();
  }

  const int q = lane >> 4, nn = lane & 15;
#pragma unroll
  for (int i = 0; i < TM; ++i) {
    const int rowb = m0 + wrow * WTM + i * 16 + q * 4;
#pragma unroll
    for (int j = 0; j < TN; ++j) {
      const int col = n0 + wcol * WTN + j * 16 + nn;
      const float bv = biasv ? biasv[col] : 0.f;
#pragma unroll
      for (int r = 0; r < 4; ++r)
        Cp[(long)(rowb + r) * N + col] = acc[i][j][r] + bv;
    }
  }
}

// ---------------------------------------------------------------------------
// Expert GEMM (round-9 structure; K split into KHALVES so resident A tile
// fits registers). Partial p = khalf*S + slice; bias in khalf 0 only.
// ---------------------------------------------------------------------------
template <int BN_, int KE_, int EPB, int NTILE, int KHALVES>
__global__ __launch_bounds__(256, 2) void egemm_k(
    const unsigned short* __restrict__ zpk, const float* __restrict__ wnT,
    const float* __restrict__ bias, const unsigned short* __restrict__ PB,
    float* __restrict__ Cbase, long partStride, int N, int nsubsTot) {
  constexpr int KT2F = KE_ / 32;
  constexpr int KT2 = KT2F / KHALVES;
  constexpr int LK = (KT2 == 8) ? 3 : (KT2 == 4) ? 2 : 1;
  constexpr int NS = BN_ / 16;
  constexpr int TN = NS / 4;
  constexpr int TM = 4;
  constexpr int S = NEXP / EPB;
  constexpr int NC = NTILE * S * KHALVES;
  constexpr int T = EPB * KT2;
  constexpr int U = ((KT2 & 3) == 0) ? 1 : (4 / KT2);

  const int tid = threadIdx.x, lane = tid & 63, wid = tid >> 6;
  const int bx = blockIdx.x;
  const int combo = bx % NC;
  const int mb = bx / NC;
  const int ntile = combo % NTILE;
  const int rest = combo / NTILE;
  const int slice = rest % S;
  const int khalf = rest / S;
  const int e0 = slice * EPB;
  const int n0 = ntile * BN_;
  float* __restrict__ Cp = Cbase + (long)(khalf * S + slice) * partStride;
  const int nn = lane & 15, q = lane >> 4;
  const bool addBias = (KHALVES == 1) || (khalf == 0);

  const unsigned short* zb =
      zpk + (long)mb * (KT2F * 4 * 512) + (long)khalf * (KT2 * 4 * 512);
  u32x4 areg[TM][KT2];
#pragma unroll
  for (int i = 0; i < TM; ++i)
#pragma unroll
    for (int kt = 0; kt < KT2; ++kt)
      areg[i][kt] = *(const u32x4*)(zb + (kt * 4 + i) * 512 + lane * 8);

  const long kstr = (long)nsubsTot * 512;
  const unsigned short* Bq = PB + ((long)e0 * KT2F + khalf * KT2) * kstr +
                             ((long)ntile * NS + wid * TN) * 512 + lane * 8;
  auto baddr = [&](int u) {
    const int ei = u >> LK, kt = u & (KT2 - 1);
    return Bq + ((long)ei * KT2F + kt) * kstr;
  };

  u32x4 ring[4][TN];
#pragma unroll
  for (int t = 0; t < 4; ++t) {
    const unsigned short* a = baddr(t < T ? t : T - 1);
#pragma unroll
    for (int j = 0; j < TN; ++j) ring[t][j] = *(const u32x4*)(a + j * 512);
  }

  f32x4 mainAcc[TM][TN] = {};

  for (int eb = 0; eb < EPB; eb += U) {
#pragma unroll
    for (int uu = 0; uu < U; ++uu) {
      const int ei = eb + uu;
      const int e = e0 + ei;
      f32x4 tmp[TM][TN];
#pragma unroll
      for (int j = 0; j < TN; ++j) {
        const float bv =
            addBias ? bias[(long)e * N + n0 + wid * (TN * 16) + j * 16 + nn]
                    : 0.f;
        f32x4 t4 = {bv, bv, bv, bv};
#pragma unroll
        for (int i = 0; i < TM; ++i) tmp[i][j] = t4;
      }
#pragma unroll
      for (int kt = 0; kt < KT2; ++kt) {
        const int slot = (uu * KT2 + kt) & 3;
#pragma unroll
        for (int i = 0; i < TM; ++i) {
          bf16x8 af = __builtin_bit_cast(bf16x8, areg[i][kt]);
#pragma unroll
          for (int j = 0; j < TN; ++j)
            tmp[i][j] = __builtin_amdgcn_mfma_f32_16x16x32_bf16(
                af, __builtin_bit_cast(bf16x8, ring[slot][j]), tmp[i][j], 0, 0,
                0);
        }
        {
          const int u = ei * KT2 + kt;
          const int un = (u + 4 < T) ? (u + 4) : (T - 1);
          const unsigned short* a = baddr(un);
#pragma unroll
          for (int j = 0; j < TN; ++j)
            ring[slot][j] = *(const u32x4*)(a + j * 512);
        }
      }
#pragma unroll
      for (int i = 0; i < TM; ++i) {
        const int rowb = mb * 64 + i * 16 + q * 4;
        f32x4 wn4 = *(const f32x4*)(wnT + (long)e * BATCH + rowb);
#pragma unroll
        for (int j = 0; j < TN; ++j) mainAcc[i][j] += wn4 * tmp[i][j];
      }
    }
  }

#pragma unroll
  for (int i = 0; i < TM; ++i) {
    const int rowb = mb * 64 + i * 16 + q * 4;
#pragma unroll
    for (int j = 0; j < TN; ++j) {
      const int col = n0 + wid * (TN * 16) + j * 16 + nn;
#pragma unroll
      for (int r = 0; r < 4; ++r)
        Cp[(long)(rowb + r) * N + col] = mainAcc[i][j][r];
    }
  }
}

// ---------------------------------------------------------------------------
// hstats (round-10 fix): COMPILE-TIME NPARTS -> fully unrolled, independent
// partial loads (round-9's runtime loop serialized ~900cy HBM loads: 56us).
// Coalesced: lane -> column group, 8 rows per block (grid 512 for C=256).
// Partial stride is PADDED by caller (+64 floats) to break 4MB channel alias.
// ---------------------------------------------------------------------------
template <int NPARTS>
__global__ void hstats_k(float* __restrict__ P, long partStride,
                         float* __restrict__ S1, float* __restrict__ S2) {
  const int c0 = (threadIdx.x & 63) * 4;
  const int rg = threadIdx.x >> 6;
  const int rb = blockIdx.x * 8;
  f32x4 s = {0.f, 0.f, 0.f, 0.f}, s2 = {0.f, 0.f, 0.f, 0.f};
#pragma unroll
  for (int it = 0; it < 2; ++it) {
    const long r = rb + it * 4 + rg;
    f32x4 v[NPARTS];
#pragma unroll
    for (int p = 0; p < NPARTS; ++p)
      v[p] = *(const f32x4*)(P + p * partStride + r * 256 + c0);
    f32x4 x = v[0];
#pragma unroll
    for (int p = 1; p < NPARTS; ++p) x += v[p];
    *(f32x4*)(P + r * 256 + c0) = x;
    s += x;
    s2 += x * x;
  }
  __shared__ f32x4 sb[256], qb[256];
  sb[threadIdx.x] = s;
  qb[threadIdx.x] = s2;
  __syncthreads();
  if (threadIdx.x < 64) {
    f32x4 ts = sb[threadIdx.x] + sb[64 + threadIdx.x] + sb[128 + threadIdx.x] +
               sb[192 + threadIdx.x];
    f32x4 tq = qb[threadIdx.x] + qb[64 + threadIdx.x] + qb[128 + threadIdx.x] +
               qb[192 + threadIdx.x];
    const int c = threadIdx.x * 4;
#pragma unroll
    for (int j = 0; j < 4; ++j) {
      atomicAdd(&S1[c + j], ts[j]);
      atomicAdd(&S2[c + j], tq[j]);
    }
  }
}

// BN stats (MNet path, unchanged).
__global__ void stats_k(const float* __restrict__ H, int C,
                        const float* __restrict__ g, const float* __restrict__ b,
                        float* __restrict__ scv, float* __restrict__ shv) {
  const int c0 = blockIdx.x * 4;
  f32x4 s = {0.f, 0.f, 0.f, 0.f}, s2 = {0.f, 0.f, 0.f, 0.f};
  for (int r = threadIdx.x; r < BATCH; r += 256) {
    f32x4 x = *(const f32x4*)(H + (long)r * C + c0);
    s += x;
    s2 += x * x;
  }
  __shared__ f32x4 sb[256], qb[256];
  sb[threadIdx.x] = s;
  qb[threadIdx.x] = s2;
  __syncthreads();
  for (int st = 128; st > 0; st >>= 1) {
    if (threadIdx.x < st) {
      sb[threadIdx.x] += sb[threadIdx.x + st];
      qb[threadIdx.x] += qb[threadIdx.x + st];
    }
    __syncthreads();
  }
  if (threadIdx.x < 4) {
    const int c = c0 + threadIdx.x;
    float mu = sb[0][threadIdx.x] * (1.f / BATCH);
    float var = qb[0][threadIdx.x] * (1.f / BATCH) - mu * mu;
    float isig = 1.f / sqrtf(var + 1e-5f);
    float sc_ = g[c] * isig;
    scv[c] = sc_;
    shv[c] = b[c] - mu * sc_;
  }
}

// zpk = packed-A-fragment bf16 of prelu(bn(H)); BN inline from S1/S2.
__global__ void zbuild_pk(const float* __restrict__ H,
                          const float* __restrict__ S1,
                          const float* __restrict__ S2,
                          const float* __restrict__ g,
                          const float* __restrict__ b,
                          const float* __restrict__ alphaPtr,
                          unsigned short* __restrict__ zpk) {
  const int c = blockIdx.x * 256 + threadIdx.x;  // 131072 total
  const float alpha = alphaPtr[0];
  const int mb = c >> 11, r = c & 2047;
  const int kt = r >> 8, q2 = r & 255;
  const int msub = q2 >> 6, ln = q2 & 63;
  const int row = mb * 64 + msub * 16 + (ln & 15);
  const int col = kt * 32 + (ln >> 4) * 8;
  const float* src = H + (long)row * 256 + col;
  u16x8 o;
#pragma unroll
  for (int h = 0; h < 2; ++h) {
    f32x4 a = *(const f32x4*)(src + h * 4);
    f32x4 s1 = *(const f32x4*)(S1 + col + h * 4);
    f32x4 s2 = *(const f32x4*)(S2 + col + h * 4);
    f32x4 gv = *(const f32x4*)(g + col + h * 4);
    f32x4 bv = *(const f32x4*)(b + col + h * 4);
#pragma unroll
    for (int j = 0; j < 4; ++j) {
      float mu = s1[j] * (1.f / BATCH);
      float var = s2[j] * (1.f / BATCH) - mu * mu;
      float sc_ = gv[j] / sqrtf(var + 1e-5f);
      float sh_ = bv[j] - mu * sc_;
      float v = fmaf(a[j], sc_, sh_);
      v = v >= 0.f ? v : alpha * v;
      o[h * 4 + j] = f2bf(v);
    }
  }
  *(u16x8*)(zpk + (long)c * 8) = o;
}

// w = prelu(bn(H3)) fp32, + global sum
__global__ void wbuild_k(const float* __restrict__ G, const float* __restrict__ scv,
                         const float* __restrict__ shv,
                         const float* __restrict__ alphaPtr,
                         float* __restrict__ w, float* __restrict__ wsum) {
  const int idx = blockIdx.x * 256 + threadIdx.x;  // 65536 threads
  const float alpha = alphaPtr[0];
  const int c0 = (idx * 4) & 63;
  f32x4 x = *(const f32x4*)(G + (long)idx * 4);
  f32x4 sv = *(const f32x4*)(scv + c0);
  f32x4 hv = *(const f32x4*)(shv + c0);
  f32x4 o;
  float part = 0.f;
#pragma unroll
  for (int j = 0; j < 4; ++j) {
    float v = fmaf(x[j], sv[j], hv[j]);
    v = v >= 0.f ? v : alpha * v;
    o[j] = v;
    part += v;
  }
  *(f32x4*)(w + (long)idx * 4) = o;
  __shared__ float sb[256];
  sb[threadIdx.x] = part;
  __syncthreads();
  for (int st = 128; st > 0; st >>= 1) {
    if (threadIdx.x < st) sb[threadIdx.x] += sb[threadIdx.x + st];
    __syncthreads();
  }
  if (threadIdx.x == 0) atomicAdd(wsum, sb[0]);
}

// Fused: wnT (blocks 0..1023) ; x0 -> packed bf16 (blocks 1024..1151).
__global__ void wnTcast_k(const float* __restrict__ w,
                          const float* __restrict__ wsum,
                          float* __restrict__ wnT, const float* __restrict__ x0,
                          unsigned short* __restrict__ x0pk) {
  const int bx = blockIdx.x;
  if (bx < 1024) {
    const int idx = bx * 256 + threadIdx.x;
    const int e = idx >> 12, b = idx & 4095;
    wnT[idx] = w[(long)b * NEXP + e] * (1.0f / wsum[0]);
  } else {
    const int c = (bx - 1024) * 256 + threadIdx.x;  // 32768
    const int mb = c >> 9, r = c & 511;
    const int kt = r >> 8, q2 = r & 255;
    const int msub = q2 >> 6, ln = q2 & 63;
    const int row = mb * 64 + msub * 16 + (ln & 15);
    const int col = kt * 32 + (ln >> 4) * 8;
    const float* src = x0 + (long)row * 64 + col;
    f32x4 a0 = *(const f32x4*)src, a1 = *(const f32x4*)(src + 4);
    u16x8 o;
#pragma unroll
    for (int j = 0; j < 4; ++j) {
      o[j] = f2bf(a0[j]);
      o[4 + j] = f2bf(a1[j]);
    }
    *(u16x8*)(x0pk + (long)c * 8) = o;
  }
}

// Fused prepack: all 7 weight tensors -> fragment-major bf16.
__global__ void prepackall_k(
    const float* __restrict__ w0, const float* __restrict__ w1,
    const float* __restrict__ w2, const float* __restrict__ w3,
    const float* __restrict__ w4, const float* __restrict__ w5,
    const float* __restrict__ w6, unsigned short* __restrict__ PB) {
  const int t = blockIdx.x * 256 + threadIdx.x;
  const float* W;
  int nsubs, shI;
  long loc;
  if (t < 4096) { W = w0; nsubs = 16; shI = 7; loc = t; }                 // mW1
  else if (t < 8192) { W = w1; nsubs = 8; shI = 8; loc = t - 4096; }      // mW2
  else if (t < 9216) { W = w2; nsubs = 4; shI = 7; loc = t - 8192; }      // mW3
  else if (t < 140288) { W = w3; nsubs = 16; shI = 6; loc = t - 9216; }   // enc0
  else if (t < 664576) { W = w4; nsubs = 16; shI = 8; loc = t - 140288; } // enc1
  else if (t < 1188864) { W = w5; nsubs = 16; shI = 8; loc = t - 664576; }// dec0
  else if (t < 1319936) { W = w6; nsubs = 4; shI = 8; loc = t - 1188864; }// dec1
  else return;
  const int lane = (int)(loc & 63);
  const long frag = loc >> 6;
  const int nsub = (int)(frag % nsubs);
  const long ktile = frag / nsubs;
  const int n = nsub * 16 + (lane & 15);
  const int k = (int)(ktile * 32 + (lane >> 4) * 8);
  const int e = k >> shI;
  const int i0 = k & ((1 << shI) - 1);
  const int O = nsubs * 16;
  const float* src = W + ((long)e * O + n) * (1 << shI) + i0;
  f32x4 a0 = *(const f32x4*)src, a1 = *(const f32x4*)(src + 4);
  u16x8 o;
#pragma unroll
  for (int j = 0; j < 4; ++j) {
    o[j] = f2bf(a0[j]);
    o[4 + j] = f2bf(a1[j]);
  }
  *(u16x8*)(PB + (long)t * 8) = o;
}

// Final reduce, compile-time NP (unrolled independent loads).
template <int NP>
__global__ void reduceN_k(const float* __restrict__ P, long partStride,
                          float* __restrict__ out, int total4) {
  const int idx = blockIdx.x * 256 + threadIdx.x;
  if (idx >= total4) return;
  f32x4 v[NP];
#pragma unroll
  for (int p = 0; p < NP; ++p)
    v[p] = *(const f32x4*)(P + p * partStride + (long)idx * 4);
  f32x4 s = v[0];
#pragma unroll
  for (int p = 1; p < NP; ++p) s += v[p];
  *(f32x4*)(out + (long)idx * 4) = s;
}

// ---------------------------------------------------------------------------
extern "C" void kernel_launch(void* const* d_in, const int* in_sizes, int n_in,
                              void* d_out, int out_size, void* d_ws, size_t ws_size,
                              hipStream_t stream) {
  const float* m0 = (const float*)d_in[0];
  const float* x0 = (const float*)d_in[1];
  const float* mW1 = (const float*)d_in[2];
  const float* mb1 = (const float*)d_in[3];
  const float* mg1 = (const float*)d_in[4];
  const float* mbe1 = (const float*)d_in[5];
  const float* ma1 = (const float*)d_in[6];
  const float* mW2 = (const float*)d_in[7];
  const float* mb2 = (const float*)d_in[8];
  const float* mg2 = (const float*)d_in[9];
  const float* mbe2 = (const float*)d_in[10];
  const float* ma2 = (const float*)d_in[11];
  const float* mW3 = (const float*)d_in[12];
  const float* mb3 = (const float*)d_in[13];
  const float* mg3 = (const float*)d_in[14];
  const float* mbe3 = (const float*)d_in[15];
  const float* ma3 = (const float*)d_in[16];
  const float* Wenc0 = (const float*)d_in[17];
  const float* benc0 = (const float*)d_in[18];
  const float* Wenc1 = (const float*)d_in[19];
  const float* benc1 = (const float*)d_in[20];
  const float* Wdec0 = (const float*)d_in[21];
  const float* bdec0 = (const float*)d_in[22];
  const float* Wdec1 = (const float*)d_in[23];
  const float* bdec1 = (const float*)d_in[24];
  const float* bng = (const float*)d_in[25];
  const float* bnb = (const float*)d_in[26];
  const float* aexp = (const float*)d_in[27];

  // Padded partial strides (break 4MB / 1MB channel aliasing).
  const long PSP = (long)BATCH * 256 + 64;  // N=256 partials
  const long PSD = (long)BATCH * 64 + 64;   // dec1 partials

  char* base = (char*)d_ws;
  size_t off = 0;
  auto alloc = [&](size_t bytes) {
    void* p = base + off;
    off = (off + bytes + 255) & ~(size_t)255;
    return p;
  };
  unsigned short* PB = (unsigned short*)alloc(1319936L * 16);  // 20.2 MB
  const long CO_mW2 = 4096, CO_mW3 = 8192, CO_e0 = 9216, CO_e1 = 140288,
             CO_d0 = 664576, CO_d1 = 1188864;
  // Pb: max(4*PSP, 16*PSD) floats ≈ 16.8 MB
  size_t pbElems = (size_t)(4 * PSP > 16 * PSD ? 4 * PSP : 16 * PSD);
  float* Pb = (float*)alloc(pbElems * 4);
  float* P0 = Pb;
  float* P1 = Pb + (long)BATCH * 256;
  unsigned short* zApk = (unsigned short*)alloc(BATCH * 256 * 2);
  unsigned short* zBpk = (unsigned short*)alloc(BATCH * 256 * 2);
  unsigned short* x0pk = (unsigned short*)alloc(BATCH * 64 * 2);
  float* wbuf = (float*)alloc(BATCH * 64 * 4);
  float* wnT = (float*)alloc((size_t)NEXP * BATCH * 4);
  float* scv = (float*)alloc(256 * 4);
  float* shv = (float*)alloc(256 * 4);
  float* zeroBuf = (float*)alloc(8192);
  float* wsum = zeroBuf;
  float* S1a = zeroBuf + 256, *S2a = zeroBuf + 512;
  float* S1b = zeroBuf + 768, *S2b = zeroBuf + 1024;
  float* S1c = zeroBuf + 1280, *S2c = zeroBuf + 1536;

  const dim3 blk(256);

  hipMemsetAsync(zeroBuf, 0, 8192, stream);
  prepackall_k<<<5156, blk, 0, stream>>>(mW1, mW2, mW3, Wenc0, Wenc1, Wdec0,
                                         Wdec1, PB);

  // ---- MNet
  gemm_k<64, 128, 2, 2, AM_PLAIN><<<dim3(64, 2, 1), blk, 0, stream>>>(
      m0, nullptr, nullptr, nullptr, PB, 128, 16, P0, mb1, 256, 2);
  stats_k<<<64, blk, 0, stream>>>(P0, 256, mg1, mbe1, scv, shv);
  gemm_k<64, 128, 2, 2, AM_BN><<<dim3(64, 1, 1), blk, 0, stream>>>(
      P0, scv, shv, ma1, PB + CO_mW2 * 8, 256, 8, P1, mb2, 128, 4);
  stats_k<<<32, blk, 0, stream>>>(P1, 128, mg2, mbe2, scv, shv);
  gemm_k<64, 64, 2, 2, AM_BN><<<dim3(64, 1, 1), blk, 0, stream>>>(
      P1, scv, shv, ma2, PB + CO_mW3 * 8, 128, 4, P0, mb3, 64, 2);
  stats_k<<<16, blk, 0, stream>>>(P0, 64, mg3, mbe3, scv, shv);
  wbuild_k<<<256, blk, 0, stream>>>(P0, scv, shv, ma3, wbuf, wsum);
  wnTcast_k<<<1152, blk, 0, stream>>>(wbuf, wsum, wnT, x0, x0pk);

  // ---- enc0: KE=64, EPB=16 -> 4 slices, grid 512, 4 partials
  egemm_k<128, 64, 16, 2, 1><<<dim3(512), blk, 0, stream>>>(
      x0pk, wnT, benc0, PB + CO_e0 * 8, Pb, PSP, 256, 16);
  hstats_k<4><<<512, blk, 0, stream>>>(Pb, PSP, S1a, S2a);
  zbuild_pk<<<512, blk, 0, stream>>>(Pb, S1a, S2a, bng, bnb, aexp, zApk);

  // ---- enc1: KE=256, EPB=32 x KHALVES=2 -> 4 partials, grid 512
  egemm_k<128, 256, 32, 2, 2><<<dim3(512), blk, 0, stream>>>(
      zApk, wnT, benc1, PB + CO_e1 * 8, Pb, PSP, 256, 16);
  hstats_k<4><<<512, blk, 0, stream>>>(Pb, PSP, S1b, S2b);
  zbuild_pk<<<512, blk, 0, stream>>>(Pb, S1b, S2b, bng, bnb, aexp, zBpk);

  // ---- dec0
  egemm_k<128, 256, 32, 2, 2><<<dim3(512), blk, 0, stream>>>(
      zBpk, wnT, bdec0, PB + CO_d0 * 8, Pb, PSP, 256, 16);
  hstats_k<4><<<512, blk, 0, stream>>>(Pb, PSP, S1c, S2c);
  zbuild_pk<<<512, blk, 0, stream>>>(Pb, S1c, S2c, bng, bnb, aexp, zApk);

  // ---- dec1: N=64, EPB=8 x KHALVES=2 -> 16 partials, grid 1024
  egemm_k<64, 256, 8, 1, 2><<<dim3(1024), blk, 0, stream>>>(
      zApk, wnT, bdec1, PB + CO_d1 * 8, Pb, PSD, 64, 4);
  reduceN_k<16><<<256, blk, 0, stream>>>(Pb, PSD, (float*)d_out, 65536);

  (void)in_sizes; (void)n_in; (void)out_size; (void)ws_size;
}

// Round 11
// 372.741 us; speedup vs baseline: 1.4018x; 1.3890x over previous
//
#include <hip/hip_runtime.h>
#include <stdint.h>

#define BATCH 4096
#define NEXP 64

typedef __bf16 bf16x8 __attribute__((ext_vector_type(8)));
typedef float f32x4 __attribute__((ext_vector_type(4)));
typedef float f32x8 __attribute__((ext_vector_type(8)));
typedef unsigned int u32x4 __attribute__((ext_vector_type(4)));
typedef unsigned short u16x4 __attribute__((ext_vector_type(4)));
typedef unsigned short u16x8 __attribute__((ext_vector_type(8)));

__device__ __forceinline__ unsigned short f2bf(float f) {
  unsigned u = __builtin_bit_cast(unsigned, f);
  u += 0x7fffu + ((u >> 16) & 1u);
  return (unsigned short)(u >> 16);
}

// async global->LDS, 16B per lane (MNet GEMM only).
__device__ __forceinline__ void async_copy16(const void* g, void* l) {
  __builtin_amdgcn_global_load_lds(
      (const __attribute__((address_space(1))) void*)(uintptr_t)g,
      (__attribute__((address_space(3))) void*)(uintptr_t)l, 16, 0, 0);
}

enum { AM_PLAIN = 0, AM_BN = 1 };

// ---------------------------------------------------------------------------
// MNet GEMM (unchanged).
// ---------------------------------------------------------------------------
template <int BM_, int BN_, int WR, int WC, int AMODE>
__global__ __launch_bounds__(256, 4) void gemm_k(
    const float* __restrict__ Af32, const float* __restrict__ scv,
    const float* __restrict__ shv, const float* __restrict__ alphaPtr,
    const unsigned short* __restrict__ PB, int K, int nsubsTot,
    float* __restrict__ Cp, const float* __restrict__ biasv, int N,
    int ktilesTot) {
  constexpr int MS = BM_ / 16;
  constexpr int NS = BN_ / 16;
  constexpr int WTM = BM_ / WR, WTN = BN_ / WC;
  constexpr int TM = WTM / 16, TN = WTN / 16;
  constexpr int PCH = MS / 2;

  __shared__ __align__(16) unsigned short As[2 * MS * 512];
  __shared__ __align__(16) unsigned short Bs[2 * NS * 512];

  const int tid = threadIdx.x;
  const int lane = tid & 63;
  const int wid = tid >> 6;
  const int wrow = wid / WC, wcol = wid % WC;

  const int m0 = blockIdx.x * BM_;
  const int ntile = blockIdx.y;
  const int n0 = ntile * BN_;

  float alpha = 0.f;
  if constexpr (AMODE == AM_BN) alpha = alphaPtr[0];

  f32x4 acc[TM][TN] = {};

  for (int kt = 0; kt < ktilesTot; ++kt) {
    const int k0 = kt * 64;

    for (int f = wid; f < 2 * NS; f += 4) {
      const int fkt = f / NS, fns = f % NS;
      const long fragIdx = (long)(k0 / 32 + fkt) * nsubsTot + (ntile * NS + fns);
      async_copy16(PB + fragIdx * 512 + lane * 8, &Bs[f * 512 + lane * 8]);
    }

#pragma unroll
    for (int p = 0; p < PCH; ++p) {
      const int id = p * 256 + tid;
      const int fA = id >> 6;
      const int q = id & 63;
      const int ksh = fA / MS, msub = fA % MS;
      const int kq = q >> 4, mrow = q & 15;
      const int m = msub * 16 + mrow;
      const int kg = k0 + ksh * 32 + kq * 8;
      const long mg = m0 + m;
      f32x8 vf;
      if constexpr (AMODE == AM_PLAIN) {
        const f32x4* src = (const f32x4*)(Af32 + mg * K + kg);
        f32x4 a0 = src[0], a1 = src[1];
#pragma unroll
        for (int j = 0; j < 4; ++j) { vf[j] = a0[j]; vf[4 + j] = a1[j]; }
      } else {
        const f32x4* src = (const f32x4*)(Af32 + mg * K + kg);
        f32x4 a0 = src[0], a1 = src[1];
        f32x4 s0 = *(const f32x4*)(scv + kg), s1 = *(const f32x4*)(scv + kg + 4);
        f32x4 h0 = *(const f32x4*)(shv + kg), h1 = *(const f32x4*)(shv + kg + 4);
#pragma unroll
        for (int j = 0; j < 4; ++j) {
          float v = fmaf(a0[j], s0[j], h0[j]);
          vf[j] = v >= 0.f ? v : alpha * v;
          float v2 = fmaf(a1[j], s1[j], h1[j]);
          vf[4 + j] = v2 >= 0.f ? v2 : alpha * v2;
        }
      }
      bf16x8 ob = __builtin_convertvector(vf, bf16x8);
      *(u16x8*)&As[id * 8] = __builtin_bit_cast(u16x8, ob);
    }
    __syncthreads();

#pragma unroll
    for (int ks = 0; ks < 2; ++ks) {
      bf16x8 af[TM], bfr[TN];
#pragma unroll
      for (int i = 0; i < TM; ++i) {
        const int msub = wrow * TM + i;
        af[i] = __builtin_bit_cast(
            bf16x8, *(const u32x4*)&As[(ks * MS + msub) * 512 + lane * 8]);
      }
#pragma unroll
      for (int j = 0; j < TN; ++j) {
        const int nsub = wcol * TN + j;
        bfr[j] = __builtin_bit_cast(
            bf16x8, *(const u32x4*)&Bs[(ks * NS + nsub) * 512 + lane * 8]);
      }
#pragma unroll
      for (int i = 0; i < TM; ++i)
#pragma unroll
        for (int j = 0; j < TN; ++j)
          acc[i][j] = __builtin_amdgcn_mfma_f32_16x16x32_bf16(af[i], bfr[j],
                                                              acc[i][j], 0, 0, 0);
    }
    __syncthreads();
  }

  const int q = lane >> 4, nn = lane & 15;
#pragma unroll
  for (int i = 0; i < TM; ++i) {
    const int rowb = m0 + wrow * WTM + i * 16 + q * 4;
#pragma unroll
    for (int j = 0; j < TN; ++j) {
      const int col = n0 + wcol * WTN + j * 16 + nn;
      const float bv = biasv ? biasv[col] : 0.f;
#pragma unroll
      for (int r = 0; r < 4; ++r)
        Cp[(long)(rowb + r) * N + col] = acc[i][j][r] + bv;
    }
  }
}

// ---------------------------------------------------------------------------
// Expert GEMM (unchanged from round 10).
// ---------------------------------------------------------------------------
template <int BN_, int KE_, int EPB, int NTILE, int KHALVES>
__global__ __launch_bounds__(256, 2) void egemm_k(
    const unsigned short* __restrict__ zpk, const float* __restrict__ wnT,
    const float* __restrict__ bias, const unsigned short* __restrict__ PB,
    float* __restrict__ Cbase, long partStride, int N, int nsubsTot) {
  constexpr int KT2F = KE_ / 32;
  constexpr int KT2 = KT2F / KHALVES;
  constexpr int LK = (KT2 == 8) ? 3 : (KT2 == 4) ? 2 : 1;
  constexpr int NS = BN_ / 16;
  constexpr int TN = NS / 4;
  constexpr int TM = 4;
  constexpr int S = NEXP / EPB;
  constexpr int NC = NTILE * S * KHALVES;
  constexpr int T = EPB * KT2;
  constexpr int U = ((KT2 & 3) == 0) ? 1 : (4 / KT2);

  const int tid = threadIdx.x, lane = tid & 63, wid = tid >> 6;
  const int bx = blockIdx.x;
  const int combo = bx % NC;
  const int mb = bx / NC;
  const int ntile = combo % NTILE;
  const int rest = combo / NTILE;
  const int slice = rest % S;
  const int khalf = rest / S;
  const int e0 = slice * EPB;
  const int n0 = ntile * BN_;
  float* __restrict__ Cp = Cbase + (long)(khalf * S + slice) * partStride;
  const int nn = lane & 15, q = lane >> 4;
  const bool addBias = (KHALVES == 1) || (khalf == 0);

  const unsigned short* zb =
      zpk + (long)mb * (KT2F * 4 * 512) + (long)khalf * (KT2 * 4 * 512);
  u32x4 areg[TM][KT2];
#pragma unroll
  for (int i = 0; i < TM; ++i)
#pragma unroll
    for (int kt = 0; kt < KT2; ++kt)
      areg[i][kt] = *(const u32x4*)(zb + (kt * 4 + i) * 512 + lane * 8);

  const long kstr = (long)nsubsTot * 512;
  const unsigned short* Bq = PB + ((long)e0 * KT2F + khalf * KT2) * kstr +
                             ((long)ntile * NS + wid * TN) * 512 + lane * 8;
  auto baddr = [&](int u) {
    const int ei = u >> LK, kt = u & (KT2 - 1);
    return Bq + ((long)ei * KT2F + kt) * kstr;
  };

  u32x4 ring[4][TN];
#pragma unroll
  for (int t = 0; t < 4; ++t) {
    const unsigned short* a = baddr(t < T ? t : T - 1);
#pragma unroll
    for (int j = 0; j < TN; ++j) ring[t][j] = *(const u32x4*)(a + j * 512);
  }

  f32x4 mainAcc[TM][TN] = {};

  for (int eb = 0; eb < EPB; eb += U) {
#pragma unroll
    for (int uu = 0; uu < U; ++uu) {
      const int ei = eb + uu;
      const int e = e0 + ei;
      f32x4 tmp[TM][TN];
#pragma unroll
      for (int j = 0; j < TN; ++j) {
        const float bv =
            addBias ? bias[(long)e * N + n0 + wid * (TN * 16) + j * 16 + nn]
                    : 0.f;
        f32x4 t4 = {bv, bv, bv, bv};
#pragma unroll
        for (int i = 0; i < TM; ++i) tmp[i][j] = t4;
      }
#pragma unroll
      for (int kt = 0; kt < KT2; ++kt) {
        const int slot = (uu * KT2 + kt) & 3;
#pragma unroll
        for (int i = 0; i < TM; ++i) {
          bf16x8 af = __builtin_bit_cast(bf16x8, areg[i][kt]);
#pragma unroll
          for (int j = 0; j < TN; ++j)
            tmp[i][j] = __builtin_amdgcn_mfma_f32_16x16x32_bf16(
                af, __builtin_bit_cast(bf16x8, ring[slot][j]), tmp[i][j], 0, 0,
                0);
        }
        {
          const int u = ei * KT2 + kt;
          const int un = (u + 4 < T) ? (u + 4) : (T - 1);
          const unsigned short* a = baddr(un);
#pragma unroll
          for (int j = 0; j < TN; ++j)
            ring[slot][j] = *(const u32x4*)(a + j * 512);
        }
      }
#pragma unroll
      for (int i = 0; i < TM; ++i) {
        const int rowb = mb * 64 + i * 16 + q * 4;
        f32x4 wn4 = *(const f32x4*)(wnT + (long)e * BATCH + rowb);
#pragma unroll
        for (int j = 0; j < TN; ++j) mainAcc[i][j] += wn4 * tmp[i][j];
      }
    }
  }

#pragma unroll
  for (int i = 0; i < TM; ++i) {
    const int rowb = mb * 64 + i * 16 + q * 4;
#pragma unroll
    for (int j = 0; j < TN; ++j) {
      const int col = n0 + wid * (TN * 16) + j * 16 + nn;
#pragma unroll
      for (int r = 0; r < 4; ++r)
        Cp[(long)(rowb + r) * N + col] = mainAcc[i][j][r];
    }
  }
}

// ---------------------------------------------------------------------------
// hstats (round-11): NO ATOMICS. Round-10 evidence: 53.5us with hbm 314GB/s,
// VALU 0.25% -- the 512-blocks x 512-atomics-per-address chain was the
// serializer (~100ns/same-address atomic * 512 = ~51us). Now each block
// writes its column partial-sums (f32x4) to BS1/BS2[colgroup][block]; the
// tiny sfin_k reduces them coalesced.
// ---------------------------------------------------------------------------
template <int NPARTS>
__global__ void hstats_k(float* __restrict__ P, long partStride,
                         f32x4* __restrict__ BS1, f32x4* __restrict__ BS2) {
  const int c0 = (threadIdx.x & 63) * 4;
  const int rg = threadIdx.x >> 6;
  const int rb = blockIdx.x * 8;
  f32x4 s = {0.f, 0.f, 0.f, 0.f}, s2 = {0.f, 0.f, 0.f, 0.f};
#pragma unroll
  for (int it = 0; it < 2; ++it) {
    const long r = rb + it * 4 + rg;
    f32x4 v[NPARTS];
#pragma unroll
    for (int p = 0; p < NPARTS; ++p)
      v[p] = *(const f32x4*)(P + p * partStride + r * 256 + c0);
    f32x4 x = v[0];
#pragma unroll
    for (int p = 1; p < NPARTS; ++p) x += v[p];
    *(f32x4*)(P + r * 256 + c0) = x;
    s += x;
    s2 += x * x;
  }
  __shared__ f32x4 sb[256], qb[256];
  sb[threadIdx.x] = s;
  qb[threadIdx.x] = s2;
  __syncthreads();
  if (threadIdx.x < 64) {
    f32x4 ts = sb[threadIdx.x] + sb[64 + threadIdx.x] + sb[128 + threadIdx.x] +
               sb[192 + threadIdx.x];
    f32x4 tq = qb[threadIdx.x] + qb[64 + threadIdx.x] + qb[128 + threadIdx.x] +
               qb[192 + threadIdx.x];
    BS1[threadIdx.x * 512 + blockIdx.x] = ts;
    BS2[threadIdx.x * 512 + blockIdx.x] = tq;
  }
}

// Reduce 512 block-partials per column-group -> finalized scv/shv.
// grid 64 (one block per 4 columns); coalesced f32x4 reads.
__global__ void sfin_k(const f32x4* __restrict__ BS1,
                       const f32x4* __restrict__ BS2,
                       const float* __restrict__ g, const float* __restrict__ b,
                       float* __restrict__ scv, float* __restrict__ shv) {
  const int cg = blockIdx.x;  // column group (4 cols)
  f32x4 s1 = BS1[cg * 512 + threadIdx.x] + BS1[cg * 512 + 256 + threadIdx.x];
  f32x4 s2 = BS2[cg * 512 + threadIdx.x] + BS2[cg * 512 + 256 + threadIdx.x];
  __shared__ f32x4 sb[256], qb[256];
  sb[threadIdx.x] = s1;
  qb[threadIdx.x] = s2;
  __syncthreads();
  for (int st = 128; st > 0; st >>= 1) {
    if (threadIdx.x < st) {
      sb[threadIdx.x] += sb[threadIdx.x + st];
      qb[threadIdx.x] += qb[threadIdx.x + st];
    }
    __syncthreads();
  }
  if (threadIdx.x < 4) {
    const int c = cg * 4 + threadIdx.x;
    float mu = sb[0][threadIdx.x] * (1.f / BATCH);
    float var = qb[0][threadIdx.x] * (1.f / BATCH) - mu * mu;
    float isig = 1.f / sqrtf(var + 1e-5f);
    float sc_ = g[c] * isig;
    scv[c] = sc_;
    shv[c] = b[c] - mu * sc_;
  }
}

// BN stats (MNet path, unchanged — no atomics, single pass).
__global__ void stats_k(const float* __restrict__ H, int C,
                        const float* __restrict__ g, const float* __restrict__ b,
                        float* __restrict__ scv, float* __restrict__ shv) {
  const int c0 = blockIdx.x * 4;
  f32x4 s = {0.f, 0.f, 0.f, 0.f}, s2 = {0.f, 0.f, 0.f, 0.f};
  for (int r = threadIdx.x; r < BATCH; r += 256) {
    f32x4 x = *(const f32x4*)(H + (long)r * C + c0);
    s += x;
    s2 += x * x;
  }
  __shared__ f32x4 sb[256], qb[256];
  sb[threadIdx.x] = s;
  qb[threadIdx.x] = s2;
  __syncthreads();
  for (int st = 128; st > 0; st >>= 1) {
    if (threadIdx.x < st) {
      sb[threadIdx.x] += sb[threadIdx.x + st];
      qb[threadIdx.x] += qb[threadIdx.x + st];
    }
    __syncthreads();
  }
  if (threadIdx.x < 4) {
    const int c = c0 + threadIdx.x;
    float mu = sb[0][threadIdx.x] * (1.f / BATCH);
    float var = qb[0][threadIdx.x] * (1.f / BATCH) - mu * mu;
    float isig = 1.f / sqrtf(var + 1e-5f);
    float sc_ = g[c] * isig;
    scv[c] = sc_;
    shv[c] = b[c] - mu * sc_;
  }
}

// zpk = packed-A-fragment bf16 of prelu(sc*H+sh); C=256 fixed.
__global__ void zbuild_pk(const float* __restrict__ H,
                          const float* __restrict__ scv,
                          const float* __restrict__ shv,
                          const float* __restrict__ alphaPtr,
                          unsigned short* __restrict__ zpk) {
  const int c = blockIdx.x * 256 + threadIdx.x;  // 131072 total
  const float alpha = alphaPtr[0];
  const int mb = c >> 11, r = c & 2047;
  const int kt = r >> 8, q2 = r & 255;
  const int msub = q2 >> 6, ln = q2 & 63;
  const int row = mb * 64 + msub * 16 + (ln & 15);
  const int col = kt * 32 + (ln >> 4) * 8;
  const float* src = H + (long)row * 256 + col;
  f32x4 a0 = *(const f32x4*)src, a1 = *(const f32x4*)(src + 4);
  f32x4 s0 = *(const f32x4*)(scv + col), s1 = *(const f32x4*)(scv + col + 4);
  f32x4 h0 = *(const f32x4*)(shv + col), h1 = *(const f32x4*)(shv + col + 4);
  u16x8 o;
#pragma unroll
  for (int j = 0; j < 4; ++j) {
    float v = fmaf(a0[j], s0[j], h0[j]);
    v = v >= 0.f ? v : alpha * v;
    o[j] = f2bf(v);
    float v2 = fmaf(a1[j], s1[j], h1[j]);
    v2 = v2 >= 0.f ? v2 : alpha * v2;
    o[4 + j] = f2bf(v2);
  }
  *(u16x8*)(zpk + (long)c * 8) = o;
}

// w = prelu(bn(H3)) fp32; per-block sums to wps (no atomic).
__global__ void wbuild_k(const float* __restrict__ G, const float* __restrict__ scv,
                         const float* __restrict__ shv,
                         const float* __restrict__ alphaPtr,
                         float* __restrict__ w, float* __restrict__ wps) {
  const int idx = blockIdx.x * 256 + threadIdx.x;  // 65536 threads
  const float alpha = alphaPtr[0];
  const int c0 = (idx * 4) & 63;
  f32x4 x = *(const f32x4*)(G + (long)idx * 4);
  f32x4 sv = *(const f32x4*)(scv + c0);
  f32x4 hv = *(const f32x4*)(shv + c0);
  f32x4 o;
  float part = 0.f;
#pragma unroll
  for (int j = 0; j < 4; ++j) {
    float v = fmaf(x[j], sv[j], hv[j]);
    v = v >= 0.f ? v : alpha * v;
    o[j] = v;
    part += v;
  }
  *(f32x4*)(w + (long)idx * 4) = o;
  __shared__ float sb[256];
  sb[threadIdx.x] = part;
  __syncthreads();
  for (int st = 128; st > 0; st >>= 1) {
    if (threadIdx.x < st) sb[threadIdx.x] += sb[threadIdx.x + st];
    __syncthreads();
  }
  if (threadIdx.x == 0) wps[blockIdx.x] = sb[0];
}

// Fused: wnT (blocks 0..1023; reduces wps[256] in-block for 1/w_sum);
// x0 -> packed bf16 (blocks 1024..1151).
__global__ void wnTcast_k(const float* __restrict__ w,
                          const float* __restrict__ wps,
                          float* __restrict__ wnT, const float* __restrict__ x0,
                          unsigned short* __restrict__ x0pk) {
  const int bx = blockIdx.x;
  if (bx < 1024) {
    __shared__ float sb[256];
    sb[threadIdx.x] = wps[threadIdx.x];
    __syncthreads();
    for (int st = 128; st > 0; st >>= 1) {
      if (threadIdx.x < st) sb[threadIdx.x] += sb[threadIdx.x + st];
      __syncthreads();
    }
    const float inv = 1.0f / sb[0];
    const int idx = bx * 256 + threadIdx.x;
    const int e = idx >> 12, b2 = idx & 4095;
    wnT[idx] = w[(long)b2 * NEXP + e] * inv;
  } else {
    const int c = (bx - 1024) * 256 + threadIdx.x;  // 32768
    const int mb = c >> 9, r = c & 511;
    const int kt = r >> 8, q2 = r & 255;
    const int msub = q2 >> 6, ln = q2 & 63;
    const int row = mb * 64 + msub * 16 + (ln & 15);
    const int col = kt * 32 + (ln >> 4) * 8;
    const float* src = x0 + (long)row * 64 + col;
    f32x4 a0 = *(const f32x4*)src, a1 = *(const f32x4*)(src + 4);
    u16x8 o;
#pragma unroll
    for (int j = 0; j < 4; ++j) {
      o[j] = f2bf(a0[j]);
      o[4 + j] = f2bf(a1[j]);
    }
    *(u16x8*)(x0pk + (long)c * 8) = o;
  }
}

// Fused prepack: all 7 weight tensors -> fragment-major bf16.
__global__ void prepackall_k(
    const float* __restrict__ w0, const float* __restrict__ w1,
    const float* __restrict__ w2, const float* __restrict__ w3,
    const float* __restrict__ w4, const float* __restrict__ w5,
    const float* __restrict__ w6, unsigned short* __restrict__ PB) {
  const int t = blockIdx.x * 256 + threadIdx.x;
  const float* W;
  int nsubs, shI;
  long loc;
  if (t < 4096) { W = w0; nsubs = 16; shI = 7; loc = t; }                 // mW1
  else if (t < 8192) { W = w1; nsubs = 8; shI = 8; loc = t - 4096; }      // mW2
  else if (t < 9216) { W = w2; nsubs = 4; shI = 7; loc = t - 8192; }      // mW3
  else if (t < 140288) { W = w3; nsubs = 16; shI = 6; loc = t - 9216; }   // enc0
  else if (t < 664576) { W = w4; nsubs = 16; shI = 8; loc = t - 140288; } // enc1
  else if (t < 1188864) { W = w5; nsubs = 16; shI = 8; loc = t - 664576; }// dec0
  else if (t < 1319936) { W = w6; nsubs = 4; shI = 8; loc = t - 1188864; }// dec1
  else return;
  const int lane = (int)(loc & 63);
  const long frag = loc >> 6;
  const int nsub = (int)(frag % nsubs);
  const long ktile = frag / nsubs;
  const int n = nsub * 16 + (lane & 15);
  const int k = (int)(ktile * 32 + (lane >> 4) * 8);
  const int e = k >> shI;
  const int i0 = k & ((1 << shI) - 1);
  const int O = nsubs * 16;
  const float* src = W + ((long)e * O + n) * (1 << shI) + i0;
  f32x4 a0 = *(const f32x4*)src, a1 = *(const f32x4*)(src + 4);
  u16x8 o;
#pragma unroll
  for (int j = 0; j < 4; ++j) {
    o[j] = f2bf(a0[j]);
    o[4 + j] = f2bf(a1[j]);
  }
  *(u16x8*)(PB + (long)t * 8) = o;
}

// Final reduce, compile-time NP (unrolled independent loads).
template <int NP>
__global__ void reduceN_k(const float* __restrict__ P, long partStride,
                          float* __restrict__ out, int total4) {
  const int idx = blockIdx.x * 256 + threadIdx.x;
  if (idx >= total4) return;
  f32x4 v[NP];
#pragma unroll
  for (int p = 0; p < NP; ++p)
    v[p] = *(const f32x4*)(P + p * partStride + (long)idx * 4);
  f32x4 s = v[0];
#pragma unroll
  for (int p = 1; p < NP; ++p) s += v[p];
  *(f32x4*)(out + (long)idx * 4) = s;
}

// ---------------------------------------------------------------------------
extern "C" void kernel_launch(void* const* d_in, const int* in_sizes, int n_in,
                              void* d_out, int out_size, void* d_ws, size_t ws_size,
                              hipStream_t stream) {
  const float* m0 = (const float*)d_in[0];
  const float* x0 = (const float*)d_in[1];
  const float* mW1 = (const float*)d_in[2];
  const float* mb1 = (const float*)d_in[3];
  const float* mg1 = (const float*)d_in[4];
  const float* mbe1 = (const float*)d_in[5];
  const float* ma1 = (const float*)d_in[6];
  const float* mW2 = (const float*)d_in[7];
  const float* mb2 = (const float*)d_in[8];
  const float* mg2 = (const float*)d_in[9];
  const float* mbe2 = (const float*)d_in[10];
  const float* ma2 = (const float*)d_in[11];
  const float* mW3 = (const float*)d_in[12];
  const float* mb3 = (const float*)d_in[13];
  const float* mg3 = (const float*)d_in[14];
  const float* mbe3 = (const float*)d_in[15];
  const float* ma3 = (const float*)d_in[16];
  const float* Wenc0 = (const float*)d_in[17];
  const float* benc0 = (const float*)d_in[18];
  const float* Wenc1 = (const float*)d_in[19];
  const float* benc1 = (const float*)d_in[20];
  const float* Wdec0 = (const float*)d_in[21];
  const float* bdec0 = (const float*)d_in[22];
  const float* Wdec1 = (const float*)d_in[23];
  const float* bdec1 = (const float*)d_in[24];
  const float* bng = (const float*)d_in[25];
  const float* bnb = (const float*)d_in[26];
  const float* aexp = (const float*)d_in[27];

  const long PSP = (long)BATCH * 256 + 64;  // N=256 partial stride (padded)
  const long PSD = (long)BATCH * 64 + 64;   // dec1 partial stride

  char* base = (char*)d_ws;
  size_t off = 0;
  auto alloc = [&](size_t bytes) {
    void* p = base + off;
    off = (off + bytes + 255) & ~(size_t)255;
    return p;
  };
  unsigned short* PB = (unsigned short*)alloc(1319936L * 16);  // 21.1 MB
  const long CO_mW2 = 4096, CO_mW3 = 8192, CO_e0 = 9216, CO_e1 = 140288,
             CO_d0 = 664576, CO_d1 = 1188864;
  size_t pbElems = (size_t)(4 * PSP > 16 * PSD ? 4 * PSP : 16 * PSD);
  float* Pb = (float*)alloc(pbElems * 4);  // 16.8 MB
  float* P0 = Pb;
  float* P1 = Pb + (long)BATCH * 256;
  unsigned short* zApk = (unsigned short*)alloc(BATCH * 256 * 2);
  unsigned short* zBpk = (unsigned short*)alloc(BATCH * 256 * 2);
  unsigned short* x0pk = (unsigned short*)alloc(BATCH * 64 * 2);
  float* wbuf = (float*)alloc(BATCH * 64 * 4);
  float* wnT = (float*)alloc((size_t)NEXP * BATCH * 4);
  f32x4* BS1 = (f32x4*)alloc(64 * 512 * 16);  // 512 KB
  f32x4* BS2 = (f32x4*)alloc(64 * 512 * 16);  // 512 KB
  float* scv = (float*)alloc(256 * 4);
  float* shv = (float*)alloc(256 * 4);
  float* wps = (float*)alloc(256 * 4);

  const dim3 blk(256);

  prepackall_k<<<5156, blk, 0, stream>>>(mW1, mW2, mW3, Wenc0, Wenc1, Wdec0,
                                         Wdec1, PB);

  // ---- MNet
  gemm_k<64, 128, 2, 2, AM_PLAIN><<<dim3(64, 2, 1), blk, 0, stream>>>(
      m0, nullptr, nullptr, nullptr, PB, 128, 16, P0, mb1, 256, 2);
  stats_k<<<64, blk, 0, stream>>>(P0, 256, mg1, mbe1, scv, shv);
  gemm_k<64, 128, 2, 2, AM_BN><<<dim3(64, 1, 1), blk, 0, stream>>>(
      P0, scv, shv, ma1, PB + CO_mW2 * 8, 256, 8, P1, mb2, 128, 4);
  stats_k<<<32, blk, 0, stream>>>(P1, 128, mg2, mbe2, scv, shv);
  gemm_k<64, 64, 2, 2, AM_BN><<<dim3(64, 1, 1), blk, 0, stream>>>(
      P1, scv, shv, ma2, PB + CO_mW3 * 8, 128, 4, P0, mb3, 64, 2);
  stats_k<<<16, blk, 0, stream>>>(P0, 64, mg3, mbe3, scv, shv);
  wbuild_k<<<256, blk, 0, stream>>>(P0, scv, shv, ma3, wbuf, wps);
  wnTcast_k<<<1152, blk, 0, stream>>>(wbuf, wps, wnT, x0, x0pk);

  // ---- enc0: KE=64, EPB=16 -> 4 slices, grid 512, 4 partials
  egemm_k<128, 64, 16, 2, 1><<<dim3(512), blk, 0, stream>>>(
      x0pk, wnT, benc0, PB + CO_e0 * 8, Pb, PSP, 256, 16);
  hstats_k<4><<<512, blk, 0, stream>>>(Pb, PSP, BS1, BS2);
  sfin_k<<<64, blk, 0, stream>>>(BS1, BS2, bng, bnb, scv, shv);
  zbuild_pk<<<512, blk, 0, stream>>>(Pb, scv, shv, aexp, zApk);

  // ---- enc1: KE=256, EPB=32 x KHALVES=2 -> 4 partials, grid 512
  egemm_k<128, 256, 32, 2, 2><<<dim3(512), blk, 0, stream>>>(
      zApk, wnT, benc1, PB + CO_e1 * 8, Pb, PSP, 256, 16);
  hstats_k<4><<<512, blk, 0, stream>>>(Pb, PSP, BS1, BS2);
  sfin_k<<<64, blk, 0, stream>>>(BS1, BS2, bng, bnb, scv, shv);
  zbuild_pk<<<512, blk, 0, stream>>>(Pb, scv, shv, aexp, zBpk);

  // ---- dec0
  egemm_k<128, 256, 32, 2, 2><<<dim3(512), blk, 0, stream>>>(
      zBpk, wnT, bdec0, PB + CO_d0 * 8, Pb, PSP, 256, 16);
  hstats_k<4><<<512, blk, 0, stream>>>(Pb, PSP, BS1, BS2);
  sfin_k<<<64, blk, 0, stream>>>(BS1, BS2, bng, bnb, scv, shv);
  zbuild_pk<<<512, blk, 0, stream>>>(Pb, scv, shv, aexp, zApk);

  // ---- dec1: N=64, EPB=8 x KHALVES=2 -> 16 partials, grid 1024
  egemm_k<64, 256, 8, 1, 2><<<dim3(1024), blk, 0, stream>>>(
      zApk, wnT, bdec1, PB + CO_d1 * 8, Pb, PSD, 64, 4);
  reduceN_k<16><<<256, blk, 0, stream>>>(Pb, PSD, (float*)d_out, 65536);

  (void)in_sizes; (void)n_in; (void)out_size; (void)ws_size;
}

// Round 12
// 354.018 us; speedup vs baseline: 1.4759x; 1.0529x over previous
//
#include <hip/hip_runtime.h>
#include <stdint.h>

#define BATCH 4096
#define NEXP 64

typedef __bf16 bf16x8 __attribute__((ext_vector_type(8)));
typedef float f32x4 __attribute__((ext_vector_type(4)));
typedef float f32x8 __attribute__((ext_vector_type(8)));
typedef unsigned int u32x4 __attribute__((ext_vector_type(4)));
typedef unsigned short u16x4 __attribute__((ext_vector_type(4)));
typedef unsigned short u16x8 __attribute__((ext_vector_type(8)));

__device__ __forceinline__ unsigned short f2bf(float f) {
  unsigned u = __builtin_bit_cast(unsigned, f);
  u += 0x7fffu + ((u >> 16) & 1u);
  return (unsigned short)(u >> 16);
}

// async global->LDS, 16B per lane.
__device__ __forceinline__ void async_copy16(const void* g, void* l) {
  __builtin_amdgcn_global_load_lds(
      (const __attribute__((address_space(1))) void*)(uintptr_t)g,
      (__attribute__((address_space(3))) void*)(uintptr_t)l, 16, 0, 0);
}

enum { AM_PLAIN = 0, AM_BN = 1 };

// ---------------------------------------------------------------------------
// MNet GEMM (unchanged).
// ---------------------------------------------------------------------------
template <int BM_, int BN_, int WR, int WC, int AMODE>
__global__ __launch_bounds__(256, 4) void gemm_k(
    const float* __restrict__ Af32, const float* __restrict__ scv,
    const float* __restrict__ shv, const float* __restrict__ alphaPtr,
    const unsigned short* __restrict__ PB, int K, int nsubsTot,
    float* __restrict__ Cp, const float* __restrict__ biasv, int N,
    int ktilesTot) {
  constexpr int MS = BM_ / 16;
  constexpr int NS = BN_ / 16;
  constexpr int WTM = BM_ / WR, WTN = BN_ / WC;
  constexpr int TM = WTM / 16, TN = WTN / 16;
  constexpr int PCH = MS / 2;

  __shared__ __align__(16) unsigned short As[2 * MS * 512];
  __shared__ __align__(16) unsigned short Bs[2 * NS * 512];

  const int tid = threadIdx.x;
  const int lane = tid & 63;
  const int wid = tid >> 6;
  const int wrow = wid / WC, wcol = wid % WC;

  const int m0 = blockIdx.x * BM_;
  const int ntile = blockIdx.y;
  const int n0 = ntile * BN_;

  float alpha = 0.f;
  if constexpr (AMODE == AM_BN) alpha = alphaPtr[0];

  f32x4 acc[TM][TN] = {};

  for (int kt = 0; kt < ktilesTot; ++kt) {
    const int k0 = kt * 64;

    for (int f = wid; f < 2 * NS; f += 4) {
      const int fkt = f / NS, fns = f % NS;
      const long fragIdx = (long)(k0 / 32 + fkt) * nsubsTot + (ntile * NS + fns);
      async_copy16(PB + fragIdx * 512 + lane * 8, &Bs[f * 512 + lane * 8]);
    }

#pragma unroll
    for (int p = 0; p < PCH; ++p) {
      const int id = p * 256 + tid;
      const int fA = id >> 6;
      const int q = id & 63;
      const int ksh = fA / MS, msub = fA % MS;
      const int kq = q >> 4, mrow = q & 15;
      const int m = msub * 16 + mrow;
      const int kg = k0 + ksh * 32 + kq * 8;
      const long mg = m0 + m;
      f32x8 vf;
      if constexpr (AMODE == AM_PLAIN) {
        const f32x4* src = (const f32x4*)(Af32 + mg * K + kg);
        f32x4 a0 = src[0], a1 = src[1];
#pragma unroll
        for (int j = 0; j < 4; ++j) { vf[j] = a0[j]; vf[4 + j] = a1[j]; }
      } else {
        const f32x4* src = (const f32x4*)(Af32 + mg * K + kg);
        f32x4 a0 = src[0], a1 = src[1];
        f32x4 s0 = *(const f32x4*)(scv + kg), s1 = *(const f32x4*)(scv + kg + 4);
        f32x4 h0 = *(const f32x4*)(shv + kg), h1 = *(const f32x4*)(shv + kg + 4);
#pragma unroll
        for (int j = 0; j < 4; ++j) {
          float v = fmaf(a0[j], s0[j], h0[j]);
          vf[j] = v >= 0.f ? v : alpha * v;
          float v2 = fmaf(a1[j], s1[j], h1[j]);
          vf[4 + j] = v2 >= 0.f ? v2 : alpha * v2;
        }
      }
      bf16x8 ob = __builtin_convertvector(vf, bf16x8);
      *(u16x8*)&As[id * 8] = __builtin_bit_cast(u16x8, ob);
    }
    __syncthreads();

#pragma unroll
    for (int ks = 0; ks < 2; ++ks) {
      bf16x8 af[TM], bfr[TN];
#pragma unroll
      for (int i = 0; i < TM; ++i) {
        const int msub = wrow * TM + i;
        af[i] = __builtin_bit_cast(
            bf16x8, *(const u32x4*)&As[(ks * MS + msub) * 512 + lane * 8]);
      }
#pragma unroll
      for (int j = 0; j < TN; ++j) {
        const int nsub = wcol * TN + j;
        bfr[j] = __builtin_bit_cast(
            bf16x8, *(const u32x4*)&Bs[(ks * NS + nsub) * 512 + lane * 8]);
      }
#pragma unroll
      for (int i = 0; i < TM; ++i)
#pragma unroll
        for (int j = 0; j < TN; ++j)
          acc[i][j] = __builtin_amdgcn_mfma_f32_16x16x32_bf16(af[i], bfr[j],
                                                              acc[i][j], 0, 0, 0);
    }
    __syncthreads();
  }

  const int q = lane >> 4, nn = lane & 15;
#pragma unroll
  for (int i = 0; i < TM; ++i) {
    const int rowb = m0 + wrow * WTM + i * 16 + q * 4;
#pragma unroll
    for (int j = 0; j < TN; ++j) {
      const int col = n0 + wcol * WTN + j * 16 + nn;
      const float bv = biasv ? biasv[col] : 0.f;
#pragma unroll
      for (int r = 0; r < 4; ++r)
        Cp[(long)(rowb + r) * N + col] = acc[i][j][r] + bv;
    }
  }
}

// ---------------------------------------------------------------------------
// Expert GEMM (round-12): A z-tile in LDS, not registers.
//   Rounds 8/11 evidence: compiler refuses to keep areg resident (VGPR_Count
//   124/100 < needed), rematerializing global A loads every kt -> T_kt~270cy
//   vs 38cy MFMA (MfmaUtil stuck at ~28%). LDS can't be remat'd away:
//   one-time async global->LDS of the KT2*4KB tile + single barrier; inner
//   loop reads A via ds_read_b128 (lane*16B -> 2-way bank alias = free).
//   Register pressure drops to ring+tmp+mainAcc (~96) -> no remat pressure.
//   B-ring (distance 4), expert-slicing, epilogue unchanged.
// ---------------------------------------------------------------------------
template <int BN_, int KE_, int EPB, int NTILE, int KHALVES>
__global__ __launch_bounds__(256, 2) void egemm_k(
    const unsigned short* __restrict__ zpk, const float* __restrict__ wnT,
    const float* __restrict__ bias, const unsigned short* __restrict__ PB,
    float* __restrict__ Cbase, long partStride, int N, int nsubsTot) {
  constexpr int KT2F = KE_ / 32;
  constexpr int KT2 = KT2F / KHALVES;
  constexpr int LK = (KT2 == 8) ? 3 : (KT2 == 4) ? 2 : 1;
  constexpr int NS = BN_ / 16;
  constexpr int TN = NS / 4;
  constexpr int TM = 4;
  constexpr int S = NEXP / EPB;
  constexpr int NC = NTILE * S * KHALVES;
  constexpr int T = EPB * KT2;
  constexpr int U = ((KT2 & 3) == 0) ? 1 : (4 / KT2);

  __shared__ __align__(16) unsigned short As[KT2 * 4 * 512];  // 8-16 KB

  const int tid = threadIdx.x, lane = tid & 63, wid = tid >> 6;
  const int bx = blockIdx.x;
  const int combo = bx % NC;
  const int mb = bx / NC;
  const int ntile = combo % NTILE;
  const int rest = combo / NTILE;
  const int slice = rest % S;
  const int khalf = rest / S;
  const int e0 = slice * EPB;
  const int n0 = ntile * BN_;
  float* __restrict__ Cp = Cbase + (long)(khalf * S + slice) * partStride;
  const int nn = lane & 15, q = lane >> 4;
  const bool addBias = (KHALVES == 1) || (khalf == 0);

  // One-time A stage: KT2*4 contiguous 1KB fragments, async DMA to LDS.
  {
    const unsigned short* zb =
        zpk + (long)mb * (KT2F * 4 * 512) + (long)khalf * (KT2 * 4 * 512);
    for (int f = wid; f < KT2 * 4; f += 4)
      async_copy16(zb + f * 512 + lane * 8, &As[f * 512 + lane * 8]);
  }

  const long kstr = (long)nsubsTot * 512;
  const unsigned short* Bq = PB + ((long)e0 * KT2F + khalf * KT2) * kstr +
                             ((long)ntile * NS + wid * TN) * 512 + lane * 8;
  auto baddr = [&](int u) {
    const int ei = u >> LK, kt = u & (KT2 - 1);
    return Bq + ((long)ei * KT2F + kt) * kstr;
  };

  u32x4 ring[4][TN];
#pragma unroll
  for (int t = 0; t < 4; ++t) {
    const unsigned short* a = baddr(t < T ? t : T - 1);
#pragma unroll
    for (int j = 0; j < TN; ++j) ring[t][j] = *(const u32x4*)(a + j * 512);
  }

  __syncthreads();  // drains the A DMA (and ring init) once

  f32x4 mainAcc[TM][TN] = {};

  for (int eb = 0; eb < EPB; eb += U) {
#pragma unroll
    for (int uu = 0; uu < U; ++uu) {
      const int ei = eb + uu;
      const int e = e0 + ei;
      f32x4 tmp[TM][TN];
#pragma unroll
      for (int j = 0; j < TN; ++j) {
        const float bv =
            addBias ? bias[(long)e * N + n0 + wid * (TN * 16) + j * 16 + nn]
                    : 0.f;
        f32x4 t4 = {bv, bv, bv, bv};
#pragma unroll
        for (int i = 0; i < TM; ++i) tmp[i][j] = t4;
      }
#pragma unroll
      for (int kt = 0; kt < KT2; ++kt) {
        const int slot = (uu * KT2 + kt) & 3;
#pragma unroll
        for (int i = 0; i < TM; ++i) {
          bf16x8 af = __builtin_bit_cast(
              bf16x8, *(const u32x4*)&As[(kt * 4 + i) * 512 + lane * 8]);
#pragma unroll
          for (int j = 0; j < TN; ++j)
            tmp[i][j] = __builtin_amdgcn_mfma_f32_16x16x32_bf16(
                af, __builtin_bit_cast(bf16x8, ring[slot][j]), tmp[i][j], 0, 0,
                0);
        }
        {
          const int u = ei * KT2 + kt;
          const int un = (u + 4 < T) ? (u + 4) : (T - 1);
          const unsigned short* a = baddr(un);
#pragma unroll
          for (int j = 0; j < TN; ++j)
            ring[slot][j] = *(const u32x4*)(a + j * 512);
        }
      }
#pragma unroll
      for (int i = 0; i < TM; ++i) {
        const int rowb = mb * 64 + i * 16 + q * 4;
        f32x4 wn4 = *(const f32x4*)(wnT + (long)e * BATCH + rowb);
#pragma unroll
        for (int j = 0; j < TN; ++j) mainAcc[i][j] += wn4 * tmp[i][j];
      }
    }
  }

#pragma unroll
  for (int i = 0; i < TM; ++i) {
    const int rowb = mb * 64 + i * 16 + q * 4;
#pragma unroll
    for (int j = 0; j < TN; ++j) {
      const int col = n0 + wid * (TN * 16) + j * 16 + nn;
#pragma unroll
      for (int r = 0; r < 4; ++r)
        Cp[(long)(rowb + r) * N + col] = mainAcc[i][j][r];
    }
  }
}

// ---------------------------------------------------------------------------
// hstats (no atomics; round-11 verified). Per-block partials to BS1/BS2.
// ---------------------------------------------------------------------------
template <int NPARTS>
__global__ void hstats_k(float* __restrict__ P, long partStride,
                         f32x4* __restrict__ BS1, f32x4* __restrict__ BS2) {
  const int c0 = (threadIdx.x & 63) * 4;
  const int rg = threadIdx.x >> 6;
  const int rb = blockIdx.x * 8;
  f32x4 s = {0.f, 0.f, 0.f, 0.f}, s2 = {0.f, 0.f, 0.f, 0.f};
#pragma unroll
  for (int it = 0; it < 2; ++it) {
    const long r = rb + it * 4 + rg;
    f32x4 v[NPARTS];
#pragma unroll
    for (int p = 0; p < NPARTS; ++p)
      v[p] = *(const f32x4*)(P + p * partStride + r * 256 + c0);
    f32x4 x = v[0];
#pragma unroll
    for (int p = 1; p < NPARTS; ++p) x += v[p];
    *(f32x4*)(P + r * 256 + c0) = x;
    s += x;
    s2 += x * x;
  }
  __shared__ f32x4 sb[256], qb[256];
  sb[threadIdx.x] = s;
  qb[threadIdx.x] = s2;
  __syncthreads();
  if (threadIdx.x < 64) {
    f32x4 ts = sb[threadIdx.x] + sb[64 + threadIdx.x] + sb[128 + threadIdx.x] +
               sb[192 + threadIdx.x];
    f32x4 tq = qb[threadIdx.x] + qb[64 + threadIdx.x] + qb[128 + threadIdx.x] +
               qb[192 + threadIdx.x];
    BS1[threadIdx.x * 512 + blockIdx.x] = ts;
    BS2[threadIdx.x * 512 + blockIdx.x] = tq;
  }
}

// Reduce 512 block-partials per column-group -> finalized scv/shv.
__global__ void sfin_k(const f32x4* __restrict__ BS1,
                       const f32x4* __restrict__ BS2,
                       const float* __restrict__ g, const float* __restrict__ b,
                       float* __restrict__ scv, float* __restrict__ shv) {
  const int cg = blockIdx.x;
  f32x4 s1 = BS1[cg * 512 + threadIdx.x] + BS1[cg * 512 + 256 + threadIdx.x];
  f32x4 s2 = BS2[cg * 512 + threadIdx.x] + BS2[cg * 512 + 256 + threadIdx.x];
  __shared__ f32x4 sb[256], qb[256];
  sb[threadIdx.x] = s1;
  qb[threadIdx.x] = s2;
  __syncthreads();
  for (int st = 128; st > 0; st >>= 1) {
    if (threadIdx.x < st) {
      sb[threadIdx.x] += sb[threadIdx.x + st];
      qb[threadIdx.x] += qb[threadIdx.x + st];
    }
    __syncthreads();
  }
  if (threadIdx.x < 4) {
    const int c = cg * 4 + threadIdx.x;
    float mu = sb[0][threadIdx.x] * (1.f / BATCH);
    float var = qb[0][threadIdx.x] * (1.f / BATCH) - mu * mu;
    float isig = 1.f / sqrtf(var + 1e-5f);
    float sc_ = g[c] * isig;
    scv[c] = sc_;
    shv[c] = b[c] - mu * sc_;
  }
}

// BN stats (MNet path).
__global__ void stats_k(const float* __restrict__ H, int C,
                        const float* __restrict__ g, const float* __restrict__ b,
                        float* __restrict__ scv, float* __restrict__ shv) {
  const int c0 = blockIdx.x * 4;
  f32x4 s = {0.f, 0.f, 0.f, 0.f}, s2 = {0.f, 0.f, 0.f, 0.f};
  for (int r = threadIdx.x; r < BATCH; r += 256) {
    f32x4 x = *(const f32x4*)(H + (long)r * C + c0);
    s += x;
    s2 += x * x;
  }
  __shared__ f32x4 sb[256], qb[256];
  sb[threadIdx.x] = s;
  qb[threadIdx.x] = s2;
  __syncthreads();
  for (int st = 128; st > 0; st >>= 1) {
    if (threadIdx.x < st) {
      sb[threadIdx.x] += sb[threadIdx.x + st];
      qb[threadIdx.x] += qb[threadIdx.x + st];
    }
    __syncthreads();
  }
  if (threadIdx.x < 4) {
    const int c = c0 + threadIdx.x;
    float mu = sb[0][threadIdx.x] * (1.f / BATCH);
    float var = qb[0][threadIdx.x] * (1.f / BATCH) - mu * mu;
    float isig = 1.f / sqrtf(var + 1e-5f);
    float sc_ = g[c] * isig;
    scv[c] = sc_;
    shv[c] = b[c] - mu * sc_;
  }
}

// zpk = packed-A-fragment bf16 of prelu(sc*H+sh); C=256 fixed.
__global__ void zbuild_pk(const float* __restrict__ H,
                          const float* __restrict__ scv,
                          const float* __restrict__ shv,
                          const float* __restrict__ alphaPtr,
                          unsigned short* __restrict__ zpk) {
  const int c = blockIdx.x * 256 + threadIdx.x;  // 131072 total
  const float alpha = alphaPtr[0];
  const int mb = c >> 11, r = c & 2047;
  const int kt = r >> 8, q2 = r & 255;
  const int msub = q2 >> 6, ln = q2 & 63;
  const int row = mb * 64 + msub * 16 + (ln & 15);
  const int col = kt * 32 + (ln >> 4) * 8;
  const float* src = H + (long)row * 256 + col;
  f32x4 a0 = *(const f32x4*)src, a1 = *(const f32x4*)(src + 4);
  f32x4 s0 = *(const f32x4*)(scv + col), s1 = *(const f32x4*)(scv + col + 4);
  f32x4 h0 = *(const f32x4*)(shv + col), h1 = *(const f32x4*)(shv + col + 4);
  u16x8 o;
#pragma unroll
  for (int j = 0; j < 4; ++j) {
    float v = fmaf(a0[j], s0[j], h0[j]);
    v = v >= 0.f ? v : alpha * v;
    o[j] = f2bf(v);
    float v2 = fmaf(a1[j], s1[j], h1[j]);
    v2 = v2 >= 0.f ? v2 : alpha * v2;
    o[4 + j] = f2bf(v2);
  }
  *(u16x8*)(zpk + (long)c * 8) = o;
}

// w = prelu(bn(H3)) fp32; per-block sums to wps (no atomic).
__global__ void wbuild_k(const float* __restrict__ G, const float* __restrict__ scv,
                         const float* __restrict__ shv,
                         const float* __restrict__ alphaPtr,
                         float* __restrict__ w, float* __restrict__ wps) {
  const int idx = blockIdx.x * 256 + threadIdx.x;  // 65536 threads
  const float alpha = alphaPtr[0];
  const int c0 = (idx * 4) & 63;
  f32x4 x = *(const f32x4*)(G + (long)idx * 4);
  f32x4 sv = *(const f32x4*)(scv + c0);
  f32x4 hv = *(const f32x4*)(shv + c0);
  f32x4 o;
  float part = 0.f;
#pragma unroll
  for (int j = 0; j < 4; ++j) {
    float v = fmaf(x[j], sv[j], hv[j]);
    v = v >= 0.f ? v : alpha * v;
    o[j] = v;
    part += v;
  }
  *(f32x4*)(w + (long)idx * 4) = o;
  __shared__ float sb[256];
  sb[threadIdx.x] = part;
  __syncthreads();
  for (int st = 128; st > 0; st >>= 1) {
    if (threadIdx.x < st) sb[threadIdx.x] += sb[threadIdx.x + st];
    __syncthreads();
  }
  if (threadIdx.x == 0) wps[blockIdx.x] = sb[0];
}

// Fused: wnT (blocks 0..1023; reduces wps[256] in-block for 1/w_sum);
// x0 -> packed bf16 (blocks 1024..1151).
__global__ void wnTcast_k(const float* __restrict__ w,
                          const float* __restrict__ wps,
                          float* __restrict__ wnT, const float* __restrict__ x0,
                          unsigned short* __restrict__ x0pk) {
  const int bx = blockIdx.x;
  if (bx < 1024) {
    __shared__ float sb[256];
    sb[threadIdx.x] = wps[threadIdx.x];
    __syncthreads();
    for (int st = 128; st > 0; st >>= 1) {
      if (threadIdx.x < st) sb[threadIdx.x] += sb[threadIdx.x + st];
      __syncthreads();
    }
    const float inv = 1.0f / sb[0];
    const int idx = bx * 256 + threadIdx.x;
    const int e = idx >> 12, b2 = idx & 4095;
    wnT[idx] = w[(long)b2 * NEXP + e] * inv;
  } else {
    const int c = (bx - 1024) * 256 + threadIdx.x;  // 32768
    const int mb = c >> 9, r = c & 511;
    const int kt = r >> 8, q2 = r & 255;
    const int msub = q2 >> 6, ln = q2 & 63;
    const int row = mb * 64 + msub * 16 + (ln & 15);
    const int col = kt * 32 + (ln >> 4) * 8;
    const float* src = x0 + (long)row * 64 + col;
    f32x4 a0 = *(const f32x4*)src, a1 = *(const f32x4*)(src + 4);
    u16x8 o;
#pragma unroll
    for (int j = 0; j < 4; ++j) {
      o[j] = f2bf(a0[j]);
      o[4 + j] = f2bf(a1[j]);
    }
    *(u16x8*)(x0pk + (long)c * 8) = o;
  }
}

// Fused prepack: all 7 weight tensors -> fragment-major bf16.
__global__ void prepackall_k(
    const float* __restrict__ w0, const float* __restrict__ w1,
    const float* __restrict__ w2, const float* __restrict__ w3,
    const float* __restrict__ w4, const float* __restrict__ w5,
    const float* __restrict__ w6, unsigned short* __restrict__ PB) {
  const int t = blockIdx.x * 256 + threadIdx.x;
  const float* W;
  int nsubs, shI;
  long loc;
  if (t < 4096) { W = w0; nsubs = 16; shI = 7; loc = t; }                 // mW1
  else if (t < 8192) { W = w1; nsubs = 8; shI = 8; loc = t - 4096; }      // mW2
  else if (t < 9216) { W = w2; nsubs = 4; shI = 7; loc = t - 8192; }      // mW3
  else if (t < 140288) { W = w3; nsubs = 16; shI = 6; loc = t - 9216; }   // enc0
  else if (t < 664576) { W = w4; nsubs = 16; shI = 8; loc = t - 140288; } // enc1
  else if (t < 1188864) { W = w5; nsubs = 16; shI = 8; loc = t - 664576; }// dec0
  else if (t < 1319936) { W = w6; nsubs = 4; shI = 8; loc = t - 1188864; }// dec1
  else return;
  const int lane = (int)(loc & 63);
  const long frag = loc >> 6;
  const int nsub = (int)(frag % nsubs);
  const long ktile = frag / nsubs;
  const int n = nsub * 16 + (lane & 15);
  const int k = (int)(ktile * 32 + (lane >> 4) * 8);
  const int e = k >> shI;
  const int i0 = k & ((1 << shI) - 1);
  const int O = nsubs * 16;
  const float* src = W + ((long)e * O + n) * (1 << shI) + i0;
  f32x4 a0 = *(const f32x4*)src, a1 = *(const f32x4*)(src + 4);
  u16x8 o;
#pragma unroll
  for (int j = 0; j < 4; ++j) {
    o[j] = f2bf(a0[j]);
    o[4 + j] = f2bf(a1[j]);
  }
  *(u16x8*)(PB + (long)t * 8) = o;
}

// Final reduce, compile-time NP (unrolled independent loads).
template <int NP>
__global__ void reduceN_k(const float* __restrict__ P, long partStride,
                          float* __restrict__ out, int total4) {
  const int idx = blockIdx.x * 256 + threadIdx.x;
  if (idx >= total4) return;
  f32x4 v[NP];
#pragma unroll
  for (int p = 0; p < NP; ++p)
    v[p] = *(const f32x4*)(P + p * partStride + (long)idx * 4);
  f32x4 s = v[0];
#pragma unroll
  for (int p = 1; p < NP; ++p) s += v[p];
  *(f32x4*)(out + (long)idx * 4) = s;
}

// ---------------------------------------------------------------------------
extern "C" void kernel_launch(void* const* d_in, const int* in_sizes, int n_in,
                              void* d_out, int out_size, void* d_ws, size_t ws_size,
                              hipStream_t stream) {
  const float* m0 = (const float*)d_in[0];
  const float* x0 = (const float*)d_in[1];
  const float* mW1 = (const float*)d_in[2];
  const float* mb1 = (const float*)d_in[3];
  const float* mg1 = (const float*)d_in[4];
  const float* mbe1 = (const float*)d_in[5];
  const float* ma1 = (const float*)d_in[6];
  const float* mW2 = (const float*)d_in[7];
  const float* mb2 = (const float*)d_in[8];
  const float* mg2 = (const float*)d_in[9];
  const float* mbe2 = (const float*)d_in[10];
  const float* ma2 = (const float*)d_in[11];
  const float* mW3 = (const float*)d_in[12];
  const float* mb3 = (const float*)d_in[13];
  const float* mg3 = (const float*)d_in[14];
  const float* mbe3 = (const float*)d_in[15];
  const float* ma3 = (const float*)d_in[16];
  const float* Wenc0 = (const float*)d_in[17];
  const float* benc0 = (const float*)d_in[18];
  const float* Wenc1 = (const float*)d_in[19];
  const float* benc1 = (const float*)d_in[20];
  const float* Wdec0 = (const float*)d_in[21];
  const float* bdec0 = (const float*)d_in[22];
  const float* Wdec1 = (const float*)d_in[23];
  const float* bdec1 = (const float*)d_in[24];
  const float* bng = (const float*)d_in[25];
  const float* bnb = (const float*)d_in[26];
  const float* aexp = (const float*)d_in[27];

  const long PSP = (long)BATCH * 256 + 64;  // N=256 partial stride (padded)
  const long PSD = (long)BATCH * 64 + 64;   // dec1 partial stride

  char* base = (char*)d_ws;
  size_t off = 0;
  auto alloc = [&](size_t bytes) {
    void* p = base + off;
    off = (off + bytes + 255) & ~(size_t)255;
    return p;
  };
  unsigned short* PB = (unsigned short*)alloc(1319936L * 16);  // 21.1 MB
  const long CO_mW2 = 4096, CO_mW3 = 8192, CO_e0 = 9216, CO_e1 = 140288,
             CO_d0 = 664576, CO_d1 = 1188864;
  size_t pbElems = (size_t)(4 * PSP > 16 * PSD ? 4 * PSP : 16 * PSD);
  float* Pb = (float*)alloc(pbElems * 4);  // 16.8 MB
  float* P0 = Pb;
  float* P1 = Pb + (long)BATCH * 256;
  unsigned short* zApk = (unsigned short*)alloc(BATCH * 256 * 2);
  unsigned short* zBpk = (unsigned short*)alloc(BATCH * 256 * 2);
  unsigned short* x0pk = (unsigned short*)alloc(BATCH * 64 * 2);
  float* wbuf = (float*)alloc(BATCH * 64 * 4);
  float* wnT = (float*)alloc((size_t)NEXP * BATCH * 4);
  f32x4* BS1 = (f32x4*)alloc(64 * 512 * 16);  // 512 KB
  f32x4* BS2 = (f32x4*)alloc(64 * 512 * 16);  // 512 KB
  float* scv = (float*)alloc(256 * 4);
  float* shv = (float*)alloc(256 * 4);
  float* wps = (float*)alloc(256 * 4);

  const dim3 blk(256);

  prepackall_k<<<5156, blk, 0, stream>>>(mW1, mW2, mW3, Wenc0, Wenc1, Wdec0,
                                         Wdec1, PB);

  // ---- MNet
  gemm_k<64, 128, 2, 2, AM_PLAIN><<<dim3(64, 2, 1), blk, 0, stream>>>(
      m0, nullptr, nullptr, nullptr, PB, 128, 16, P0, mb1, 256, 2);
  stats_k<<<64, blk, 0, stream>>>(P0, 256, mg1, mbe1, scv, shv);
  gemm_k<64, 128, 2, 2, AM_BN><<<dim3(64, 1, 1), blk, 0, stream>>>(
      P0, scv, shv, ma1, PB + CO_mW2 * 8, 256, 8, P1, mb2, 128, 4);
  stats_k<<<32, blk, 0, stream>>>(P1, 128, mg2, mbe2, scv, shv);
  gemm_k<64, 64, 2, 2, AM_BN><<<dim3(64, 1, 1), blk, 0, stream>>>(
      P1, scv, shv, ma2, PB + CO_mW3 * 8, 128, 4, P0, mb3, 64, 2);
  stats_k<<<16, blk, 0, stream>>>(P0, 64, mg3, mbe3, scv, shv);
  wbuild_k<<<256, blk, 0, stream>>>(P0, scv, shv, ma3, wbuf, wps);
  wnTcast_k<<<1152, blk, 0, stream>>>(wbuf, wps, wnT, x0, x0pk);

  // ---- enc0: KE=64, EPB=16 -> 4 slices, grid 512, 4 partials
  egemm_k<128, 64, 16, 2, 1><<<dim3(512), blk, 0, stream>>>(
      x0pk, wnT, benc0, PB + CO_e0 * 8, Pb, PSP, 256, 16);
  hstats_k<4><<<512, blk, 0, stream>>>(Pb, PSP, BS1, BS2);
  sfin_k<<<64, blk, 0, stream>>>(BS1, BS2, bng, bnb, scv, shv);
  zbuild_pk<<<512, blk, 0, stream>>>(Pb, scv, shv, aexp, zApk);

  // ---- enc1: KE=256, EPB=32 x KHALVES=2 -> 4 partials, grid 512
  egemm_k<128, 256, 32, 2, 2><<<dim3(512), blk, 0, stream>>>(
      zApk, wnT, benc1, PB + CO_e1 * 8, Pb, PSP, 256, 16);
  hstats_k<4><<<512, blk, 0, stream>>>(Pb, PSP, BS1, BS2);
  sfin_k<<<64, blk, 0, stream>>>(BS1, BS2, bng, bnb, scv, shv);
  zbuild_pk<<<512, blk, 0, stream>>>(Pb, scv, shv, aexp, zBpk);

  // ---- dec0
  egemm_k<128, 256, 32, 2, 2><<<dim3(512), blk, 0, stream>>>(
      zBpk, wnT, bdec0, PB + CO_d0 * 8, Pb, PSP, 256, 16);
  hstats_k<4><<<512, blk, 0, stream>>>(Pb, PSP, BS1, BS2);
  sfin_k<<<64, blk, 0, stream>>>(BS1, BS2, bng, bnb, scv, shv);
  zbuild_pk<<<512, blk, 0, stream>>>(Pb, scv, shv, aexp, zApk);

  // ---- dec1: N=64, EPB=8 x KHALVES=2 -> 16 partials, grid 1024
  egemm_k<64, 256, 8, 1, 2><<<dim3(1024), blk, 0, stream>>>(
      zApk, wnT, bdec1, PB + CO_d1 * 8, Pb, PSD, 64, 4);
  reduceN_k<16><<<256, blk, 0, stream>>>(Pb, PSD, (float*)d_out, 65536);

  (void)in_sizes; (void)n_in; (void)out_size; (void)ws_size;
}